// Round 11
// baseline (682.019 us; speedup 1.0000x reference)
//
#include <hip/hip_runtime.h>
#include <hip/hip_bf16.h>

#define N_NODES 203769
#define N_EDGES 234355
#define F_IN    165
#define F_HID   128
#define F_OUT   64
#define BN_EPS  1e-5f
#define NB_SCAN 796   // ceil(N_NODES/256)
#define KP      192   // K padded to 6*32 for mfma_16x16x32
#define NBLK    4096  // aggregation grid (atomic tail gone -> more TLP is free)
#define GB128C  1593  // ceil(N_NODES/128)

typedef short bf16x8 __attribute__((ext_vector_type(8)));
typedef unsigned short u16x8 __attribute__((ext_vector_type(8)));
typedef float f32x4 __attribute__((ext_vector_type(4)));
typedef float f32x4u __attribute__((ext_vector_type(4), aligned(4)));  // 4B-aligned vec load

__device__ __forceinline__ unsigned short f2bf(float f) {
    unsigned int u = __builtin_bit_cast(unsigned int, f);
    u += 0x7fffu + ((u >> 16) & 1u);   // RNE
    return (unsigned short)(u >> 16);
}
__device__ __forceinline__ float bf2f(unsigned short h) {
    unsigned int u = ((unsigned int)h) << 16;
    return __builtin_bit_cast(float, u);
}

// ---------------------------------------------------------------------------
// CSR build
// ---------------------------------------------------------------------------
__global__ void k_count(const int* __restrict__ dst, int* __restrict__ cnt) {
    int e = blockIdx.x * 256 + threadIdx.x;
    if (e < N_EDGES) atomicAdd(&cnt[dst[e]], 1);
}

__global__ __launch_bounds__(256) void k_scanA(const int* __restrict__ cnt,
                                               int* __restrict__ partials) {
    __shared__ int sm[256];
    int t = threadIdx.x;
    int i = blockIdx.x * 256 + t;
    int v = (i < N_NODES) ? cnt[i] : 0;
    sm[t] = v;
    __syncthreads();
    for (int off = 128; off > 0; off >>= 1) {
        if (t < off) sm[t] += sm[t + off];
        __syncthreads();
    }
    if (t == 0) partials[blockIdx.x] = sm[0];
}

__global__ __launch_bounds__(1024) void k_scanB(int* __restrict__ partials,
                                                int* __restrict__ row_ptr) {
    __shared__ int sm[1024];
    int t = threadIdx.x;
    int v = (t < NB_SCAN) ? partials[t] : 0;
    sm[t] = v;
    __syncthreads();
    for (int off = 1; off < 1024; off <<= 1) {
        int add = (t >= off) ? sm[t - off] : 0;
        __syncthreads();
        sm[t] += add;
        __syncthreads();
    }
    if (t < NB_SCAN) partials[t] = sm[t] - v;   // exclusive
    if (t == NB_SCAN - 1) row_ptr[N_NODES] = sm[t];  // = E
}

__global__ __launch_bounds__(256) void k_scanC(const int* __restrict__ cnt,
                                               const int* __restrict__ partials,
                                               int* __restrict__ row_ptr,
                                               int* __restrict__ cursor,
                                               float* __restrict__ dinv) {
    __shared__ int sm[256];
    int t = threadIdx.x;
    int i = blockIdx.x * 256 + t;
    int v = (i < N_NODES) ? cnt[i] : 0;
    sm[t] = v;
    __syncthreads();
    for (int off = 1; off < 256; off <<= 1) {
        int add = (t >= off) ? sm[t - off] : 0;
        __syncthreads();
        sm[t] += add;
        __syncthreads();
    }
    if (i < N_NODES) {
        int p = partials[blockIdx.x] + sm[t] - v;  // exclusive prefix
        row_ptr[i] = p;
        cursor[i] = p;
        dinv[i] = rsqrtf(1.0f + (float)v);  // +1 self loop
    }
}

__global__ void k_scatter(const int* __restrict__ src, const int* __restrict__ dst,
                          int* __restrict__ cursor, int* __restrict__ csr_src) {
    int e = blockIdx.x * 256 + threadIdx.x;
    if (e < N_EDGES) {
        int pos = atomicAdd(&cursor[dst[e]], 1);
        csr_src[pos] = src[e];
    }
}

// ---------------------------------------------------------------------------
// W1 -> bf16, MFMA-fragment-tiled: wb unit o = ((ng*6+kb)*4+quad)*16+l16,
// element j in o*8+j, value = W1[k][n] with n=ng*16+l16, k=kb*32+quad*8+j.
// ---------------------------------------------------------------------------
__global__ void k_cvt_w(const float* __restrict__ W1, unsigned short* __restrict__ wb) {
    int i = blockIdx.x * 256 + threadIdx.x;
    if (i < F_HID * KP) {
        int n = i / KP, k = i - n * KP;
        float v = (k < F_IN) ? W1[k * F_HID + n] : 0.0f;
        int ng = n >> 4, l16 = n & 15, kb = k >> 5, quad = (k >> 3) & 3, j = k & 7;
        wb[((((size_t)ng * 6 + kb) * 4 + quad) * 16 + l16) * 8 + j] = f2bf(v);
    }
}

// ---------------------------------------------------------------------------
// W2 -> split bf16 (hi + lo), MFMA-fragment-tiled (K=128 -> kb 0..3, N=64 ->
// ng 0..3). 3-term MFMA keeps GEMM2 error ~2^-18 relative (R8: absmax held).
// ---------------------------------------------------------------------------
__global__ void k_cvt_w2(const float* __restrict__ W2,
                         unsigned short* __restrict__ w2h,
                         unsigned short* __restrict__ w2l) {
    int i = blockIdx.x * 256 + threadIdx.x;
    if (i < F_HID * F_OUT) {
        int k = i / F_OUT, n = i - k * F_OUT;
        float v = W2[i];
        unsigned short h = f2bf(v);
        float lo = v - bf2f(h);
        int ng = n >> 4, l16 = n & 15, kb = k >> 5, quad = (k >> 3) & 3, j = k & 7;
        size_t idx = ((((size_t)ng * 4 + kb) * 4 + quad) * 16 + l16) * 8 + j;
        w2h[idx] = h;
        w2l[idx] = f2bf(lo);
    }
}

// ---------------------------------------------------------------------------
// GEMM1 (R12): h1s[N,128] = (x @ W1) * dinv[row], NO LDS / NO BARRIERS,
// x read DIRECTLY (cvt_x fused; -156MB xa traffic, -1 launch). Same
// line-coalesced A-fragment pattern proven by k_mfma2: lane (l16,quad)
// reads row rg*16+l16, 32B at k0=kb*32+quad*8 -> wave covers 16 rows x
// 128B contiguous. x rows are 660B-strided (4B-aligned) -> f32x4u loads.
// kb=5 is the padded K-block: guarded scalar loads (also avoids OOB on
// the last row).
// ---------------------------------------------------------------------------
__global__ __launch_bounds__(256) void k_mfma1(const float* __restrict__ x,
                                               const unsigned short* __restrict__ wb,
                                               const float* __restrict__ dinv,
                                               float* __restrict__ h1s) {
    const int t = threadIdx.x;
    const int wv = t >> 6;
    const int lane = t & 63;
    const int l16 = lane & 15;
    const int quad = lane >> 4;
    const int rg0 = blockIdx.x * 8 + wv * 2;
    const int lq = quad * 16 + l16;

    f32x4 acc[2][8];
#pragma unroll
    for (int mt = 0; mt < 2; mt++)
#pragma unroll
        for (int nt = 0; nt < 8; nt++)
            acc[mt][nt] = (f32x4){0.0f, 0.0f, 0.0f, 0.0f};

#pragma unroll
    for (int kb = 0; kb < 6; kb++) {
        const int k0 = kb * 32 + quad * 8;
        bf16x8 a[2], b[8];
#pragma unroll
        for (int mt = 0; mt < 2; mt++) {
            int row = (rg0 + mt) * 16 + l16;
            u16x8 u;
            if (row < N_NODES) {
                const float* rp = x + (size_t)row * F_IN + k0;
                if (kb < 5) {                 // k0+8 <= 160 <= F_IN: full vec
                    f32x4u v0 = *(const f32x4u*)rp;
                    f32x4u v1 = *(const f32x4u*)(rp + 4);
                    u[0] = f2bf(v0[0]); u[1] = f2bf(v0[1]);
                    u[2] = f2bf(v0[2]); u[3] = f2bf(v0[3]);
                    u[4] = f2bf(v1[0]); u[5] = f2bf(v1[1]);
                    u[6] = f2bf(v1[2]); u[7] = f2bf(v1[3]);
                } else {                       // padded tail, guarded scalar
#pragma unroll
                    for (int j = 0; j < 8; j++) {
                        int k = k0 + j;
                        u[j] = (k < F_IN) ? f2bf(rp[j]) : (unsigned short)0;
                    }
                }
            } else {
#pragma unroll
                for (int j = 0; j < 8; j++) u[j] = 0;
            }
            a[mt] = __builtin_bit_cast(bf16x8, u);
        }
#pragma unroll
        for (int nt = 0; nt < 8; nt++)
            b[nt] = *(const bf16x8*)&wb[(((size_t)nt * 6 + kb) * 64 + lq) * 8];
#pragma unroll
        for (int mt = 0; mt < 2; mt++)
#pragma unroll
            for (int nt = 0; nt < 8; nt++)
                acc[mt][nt] = __builtin_amdgcn_mfma_f32_16x16x32_bf16(
                    a[mt], b[nt], acc[mt][nt], 0, 0, 0);
    }

    // epilogue: C/D col = lane&15, row = quad*4 + reg; scale by dinv[row]
#pragma unroll
    for (int mt = 0; mt < 2; mt++) {
#pragma unroll
        for (int rgi = 0; rgi < 4; rgi++) {
            int grow = (rg0 + mt) * 16 + quad * 4 + rgi;
            if (grow < N_NODES) {
                float dv = dinv[grow];
                float* orow = h1s + (size_t)grow * F_HID + l16;
#pragma unroll
                for (int nt = 0; nt < 8; nt++)
                    orow[nt * 16] = acc[mt][nt][rgi] * dv;
            }
        }
    }
}

// ---------------------------------------------------------------------------
// GEMM2: h2s[N,64] = (relu(bn1(out1)) @ W2) * dinv, split-bf16 MFMA,
// NO LDS / NO BARRIERS (R8: 106 -> <78us, absmax held).
// ---------------------------------------------------------------------------
__global__ __launch_bounds__(256) void k_mfma2(const float* __restrict__ out1,
                                               const float* __restrict__ sc1,
                                               const float* __restrict__ sh1,
                                               const unsigned short* __restrict__ w2h,
                                               const unsigned short* __restrict__ w2l,
                                               const float* __restrict__ dinv,
                                               float* __restrict__ h2s) {
    const int t = threadIdx.x;
    const int wv = t >> 6;
    const int lane = t & 63;
    const int l16 = lane & 15;
    const int quad = lane >> 4;
    const int rg0 = blockIdx.x * 8 + wv * 2;
    const int lq = quad * 16 + l16;

    f32x4 acc[2][4];
#pragma unroll
    for (int mt = 0; mt < 2; mt++)
#pragma unroll
        for (int nt = 0; nt < 4; nt++)
            acc[mt][nt] = (f32x4){0.0f, 0.0f, 0.0f, 0.0f};

#pragma unroll
    for (int kb = 0; kb < 4; kb++) {
        const int k0 = kb * 32 + quad * 8;
        float4 sA = *(const float4*)&sc1[k0];
        float4 sB = *(const float4*)&sc1[k0 + 4];
        float4 hA = *(const float4*)&sh1[k0];
        float4 hB = *(const float4*)&sh1[k0 + 4];
        float sv[8] = {sA.x, sA.y, sA.z, sA.w, sB.x, sB.y, sB.z, sB.w};
        float hv[8] = {hA.x, hA.y, hA.z, hA.w, hB.x, hB.y, hB.z, hB.w};

        bf16x8 bh[4], bl[4];
#pragma unroll
        for (int nt = 0; nt < 4; nt++) {
            size_t u = ((((size_t)nt * 4 + kb) * 64) + lq) * 8;
            bh[nt] = *(const bf16x8*)&w2h[u];
            bl[nt] = *(const bf16x8*)&w2l[u];
        }

        bf16x8 ah[2], al[2];
#pragma unroll
        for (int mt = 0; mt < 2; mt++) {
            int row = (rg0 + mt) * 16 + l16;
            float v[8];
            if (row < N_NODES) {
                const float* rp = out1 + (size_t)row * F_HID + k0;
                float4 v0 = *(const float4*)rp;
                float4 v1 = *(const float4*)(rp + 4);
                v[0] = v0.x; v[1] = v0.y; v[2] = v0.z; v[3] = v0.w;
                v[4] = v1.x; v[5] = v1.y; v[6] = v1.z; v[7] = v1.w;
            } else {
#pragma unroll
                for (int j = 0; j < 8; j++) v[j] = 0.0f;
            }
            u16x8 uh, ul;
#pragma unroll
            for (int j = 0; j < 8; j++) {
                float f = fmaxf(fmaf(v[j], sv[j], hv[j]), 0.0f);
                unsigned short hb = f2bf(f);
                uh[j] = hb;
                ul[j] = f2bf(f - bf2f(hb));
            }
            ah[mt] = __builtin_bit_cast(bf16x8, uh);
            al[mt] = __builtin_bit_cast(bf16x8, ul);
        }

#pragma unroll
        for (int mt = 0; mt < 2; mt++)
#pragma unroll
            for (int nt = 0; nt < 4; nt++) {
                acc[mt][nt] = __builtin_amdgcn_mfma_f32_16x16x32_bf16(
                    ah[mt], bh[nt], acc[mt][nt], 0, 0, 0);
                acc[mt][nt] = __builtin_amdgcn_mfma_f32_16x16x32_bf16(
                    al[mt], bh[nt], acc[mt][nt], 0, 0, 0);
                acc[mt][nt] = __builtin_amdgcn_mfma_f32_16x16x32_bf16(
                    ah[mt], bl[nt], acc[mt][nt], 0, 0, 0);
            }
    }

#pragma unroll
    for (int mt = 0; mt < 2; mt++) {
#pragma unroll
        for (int rgi = 0; rgi < 4; rgi++) {
            int grow = (rg0 + mt) * 16 + quad * 4 + rgi;
            if (grow < N_NODES) {
                float dv = dinv[grow];
                float* orow = h2s + (size_t)grow * F_OUT + l16;
#pragma unroll
                for (int nt = 0; nt < 4; nt++)
                    orow[nt * 16] = acc[mt][nt][rgi] * dv;
            }
        }
    }
}

// ---------------------------------------------------------------------------
// Aggregation: single-pass CSR chase, BN stats as per-block partials.
// R12: grid 1024 -> 4096. The R1/R4 "grid regression" slope (0.109us/blk)
// was the same-address atomic tail, removed in R6 -> more blocks now buy
// gather-latency hiding (serial node-iters/thread 25 -> ~6).
// ---------------------------------------------------------------------------
template <int C, int TPN, int NPB>
__global__ __launch_bounds__(256) void k_aggr(const float* __restrict__ hs,
                                              const int* __restrict__ row_ptr,
                                              const int* __restrict__ csr_src,
                                              const float* __restrict__ dinv,
                                              float* __restrict__ out,
                                              float* __restrict__ psum,
                                              float* __restrict__ psq) {
    const int t = threadIdx.x;
    const int q = t & (TPN - 1);
    const int slot = t / TPN;
    float s0 = 0, s1 = 0, s2 = 0, s3 = 0;
    float q0 = 0, q1 = 0, q2 = 0, q3 = 0;

    for (int node = blockIdx.x * NPB + slot; node < N_NODES;
         node += gridDim.x * NPB) {
        int beg = row_ptr[node];
        int end = row_ptr[node + 1];
        float4 acc = *(const float4*)&hs[(size_t)node * C + q * 4];
        for (int e = beg; e < end; e++) {
            int s = csr_src[e];
            float4 v = *(const float4*)&hs[(size_t)s * C + q * 4];
            acc.x += v.x; acc.y += v.y; acc.z += v.z; acc.w += v.w;
        }
        float dv = dinv[node];
        acc.x *= dv; acc.y *= dv; acc.z *= dv; acc.w *= dv;
        *(float4*)&out[(size_t)node * C + q * 4] = acc;
        s0 += acc.x; s1 += acc.y; s2 += acc.z; s3 += acc.w;
        q0 = fmaf(acc.x, acc.x, q0); q1 = fmaf(acc.y, acc.y, q1);
        q2 = fmaf(acc.z, acc.z, q2); q3 = fmaf(acc.w, acc.w, q3);
    }

    __shared__ float sm[256 * 4];
    __shared__ float sq[256 * 4];
    sm[t * 4 + 0] = s0; sm[t * 4 + 1] = s1; sm[t * 4 + 2] = s2; sm[t * 4 + 3] = s3;
    sq[t * 4 + 0] = q0; sq[t * 4 + 1] = q1; sq[t * 4 + 2] = q2; sq[t * 4 + 3] = q3;
    __syncthreads();
    if (t < TPN) {
#pragma unroll
        for (int sl = 1; sl < NPB; sl++) {
            int u = (sl * TPN + t) * 4;
            s0 += sm[u + 0]; s1 += sm[u + 1]; s2 += sm[u + 2]; s3 += sm[u + 3];
            q0 += sq[u + 0]; q1 += sq[u + 1]; q2 += sq[u + 2]; q3 += sq[u + 3];
        }
        float4 o1 = {s0, s1, s2, s3};
        float4 o2 = {q0, q1, q2, q3};
        *(float4*)&psum[(size_t)blockIdx.x * C + t * 4] = o1;
        *(float4*)&psq [(size_t)blockIdx.x * C + t * 4] = o2;
    }
}

// ---------------------------------------------------------------------------
// Reduce NBLK x C partials -> scale/shift.
// ---------------------------------------------------------------------------
template <int C>
__global__ __launch_bounds__(1024) void k_bn_fin(const float* __restrict__ psum,
                                                 const float* __restrict__ psq,
                                                 const float* __restrict__ g,
                                                 const float* __restrict__ be,
                                                 float* __restrict__ sc,
                                                 float* __restrict__ sh) {
    const int t = threadIdx.x;
    const int c = t & (C - 1);
    const int gg = t / C;          // 0..G-1
    const int G = 1024 / C;
    const int BPG = NBLK / G;
    float s = 0.0f, sq_ = 0.0f;
    for (int i = 0; i < BPG; i++) {
        int b = gg * BPG + i;
        s   += psum[(size_t)b * C + c];
        sq_ += psq [(size_t)b * C + c];
    }
    __shared__ float sm[1024];
    __shared__ float s2[1024];
    sm[t] = s;
    s2[t] = sq_;
    __syncthreads();
    for (int off = G / 2; off > 0; off >>= 1) {
        if (gg < off) {
            sm[t] += sm[t + off * C];
            s2[t] += s2[t + off * C];
        }
        __syncthreads();
    }
    if (gg == 0) {
        const float invn = 1.0f / (float)N_NODES;
        float mean = sm[c] * invn;
        float var = s2[c] * invn - mean * mean;
        float rstd = rsqrtf(var + BN_EPS);
        float scale = g[c] * rstd;
        sc[c] = scale;
        sh[c] = fmaf(-mean, scale, be[c]);
    }
}

// ---------------------------------------------------------------------------
// Final: hf = bn2(out2) -> d_out; z = relu(hf@Wp1+bp1)@Wp2+bp2
// ---------------------------------------------------------------------------
__global__ __launch_bounds__(256) void k_final(const float* __restrict__ out2,
                                               const float* __restrict__ sc2,
                                               const float* __restrict__ sh2,
                                               const float* __restrict__ Wp1,
                                               const float* __restrict__ bp1,
                                               const float* __restrict__ Wp2,
                                               const float* __restrict__ bp2,
                                               float* __restrict__ out) {
    __shared__ float hs[64 * 68];   // 17.4 KB
    __shared__ float as_[64 * 68];  // 17.4 KB
    const int row0 = blockIdx.x * 64;
    const int t = threadIdx.x;

    {
        const float4* src = (const float4*)out2;
        float4* dsth = (float4*)out;
#pragma unroll
        for (int i = 0; i < 4; i++) {
            int f4 = t + i * 256;         // 0..1023
            int r = f4 >> 4;
            int c4 = f4 & 15;
            int grow = row0 + r;
            float4 v = {0, 0, 0, 0};
            if (grow < N_NODES) v = src[(size_t)grow * 16 + c4];
            int c = c4 * 4;
            v.x = fmaf(v.x, sc2[c + 0], sh2[c + 0]);
            v.y = fmaf(v.y, sc2[c + 1], sh2[c + 1]);
            v.z = fmaf(v.z, sc2[c + 2], sh2[c + 2]);
            v.w = fmaf(v.w, sc2[c + 3], sh2[c + 3]);
            if (grow < N_NODES) dsth[(size_t)grow * 16 + c4] = v;
            *(float4*)&hs[r * 68 + c] = v;
        }
    }
    __syncthreads();

    const int c0 = (t & 15) * 4;
    const int r0 = (t >> 4) * 4;

    // GEMM A: a = relu(hs @ Wp1 + bp1)
    {
        float acc[4][4];
#pragma unroll
        for (int r = 0; r < 4; r++)
#pragma unroll
            for (int c = 0; c < 4; c++) acc[r][c] = 0.0f;
#pragma unroll 2
        for (int k4 = 0; k4 < 64; k4 += 4) {
            float4 xv[4];
#pragma unroll
            for (int r = 0; r < 4; r++)
                xv[r] = *(const float4*)&hs[(r0 + r) * 68 + k4];
            float4 w[4];
#pragma unroll
            for (int j = 0; j < 4; j++)
                w[j] = *(const float4*)&Wp1[(k4 + j) * 64 + c0];
#pragma unroll
            for (int r = 0; r < 4; r++) {
                const float xr[4] = {xv[r].x, xv[r].y, xv[r].z, xv[r].w};
#pragma unroll
                for (int j = 0; j < 4; j++) {
                    acc[r][0] = fmaf(xr[j], w[j].x, acc[r][0]);
                    acc[r][1] = fmaf(xr[j], w[j].y, acc[r][1]);
                    acc[r][2] = fmaf(xr[j], w[j].z, acc[r][2]);
                    acc[r][3] = fmaf(xr[j], w[j].w, acc[r][3]);
                }
            }
        }
        float4 b = *(const float4*)&bp1[c0];
#pragma unroll
        for (int r = 0; r < 4; r++) {
            float4 o = {fmaxf(acc[r][0] + b.x, 0.0f), fmaxf(acc[r][1] + b.y, 0.0f),
                        fmaxf(acc[r][2] + b.z, 0.0f), fmaxf(acc[r][3] + b.w, 0.0f)};
            *(float4*)&as_[(r0 + r) * 68 + c0] = o;
        }
    }
    __syncthreads();

    // GEMM B: z = a @ Wp2 + bp2
    {
        float acc[4][4];
#pragma unroll
        for (int r = 0; r < 4; r++)
#pragma unroll
            for (int c = 0; c < 4; c++) acc[r][c] = 0.0f;
#pragma unroll 2
        for (int k4 = 0; k4 < 64; k4 += 4) {
            float4 xv[4];
#pragma unroll
            for (int r = 0; r < 4; r++)
                xv[r] = *(const float4*)&as_[(r0 + r) * 68 + k4];
            float4 w[4];
#pragma unroll
            for (int j = 0; j < 4; j++)
                w[j] = *(const float4*)&Wp2[(k4 + j) * 64 + c0];
#pragma unroll
            for (int r = 0; r < 4; r++) {
                const float xr[4] = {xv[r].x, xv[r].y, xv[r].z, xv[r].w};
#pragma unroll
                for (int j = 0; j < 4; j++) {
                    acc[r][0] = fmaf(xr[j], w[j].x, acc[r][0]);
                    acc[r][1] = fmaf(xr[j], w[j].y, acc[r][1]);
                    acc[r][2] = fmaf(xr[j], w[j].z, acc[r][2]);
                    acc[r][3] = fmaf(xr[j], w[j].w, acc[r][3]);
                }
            }
        }
        float4 b = *(const float4*)&bp2[c0];
        float* zout = out + (size_t)N_NODES * 64;
#pragma unroll
        for (int r = 0; r < 4; r++) {
            int row = row0 + r0 + r;
            if (row < N_NODES) {
                float4 o = {acc[r][0] + b.x, acc[r][1] + b.y,
                            acc[r][2] + b.z, acc[r][3] + b.w};
                *(float4*)&zout[(size_t)row * 64 + c0] = o;
            }
        }
    }
}

// ---------------------------------------------------------------------------
// launch
// ---------------------------------------------------------------------------
extern "C" void kernel_launch(void* const* d_in, const int* in_sizes, int n_in,
                              void* d_out, int out_size, void* d_ws, size_t ws_size,
                              hipStream_t stream) {
    const float* x   = (const float*)d_in[0];
    const int*   ei  = (const int*)d_in[1];
    const float* W1  = (const float*)d_in[2];
    // b1 (d_in[3]) skipped: column-constant shift cancelled by BN1
    const float* g1  = (const float*)d_in[4];
    const float* be1 = (const float*)d_in[5];
    const float* W2  = (const float*)d_in[6];
    // b2 (d_in[7]) skipped: cancelled by BN2
    const float* g2  = (const float*)d_in[8];
    const float* be2 = (const float*)d_in[9];
    const float* Wp1 = (const float*)d_in[10];
    const float* bp1 = (const float*)d_in[11];
    const float* Wp2 = (const float*)d_in[12];
    const float* bp2 = (const float*)d_in[13];

    const int* src = ei;            // edge_index[0]
    const int* dst = ei + N_EDGES;  // edge_index[1]

    float* ws = (float*)d_ws;
    float* A    = ws;                          // h1s (N*128) / h2s (N*64)
    float* B    = A + (size_t)N_NODES * 128;   // out1 (N*128) / out2 (N*64)
    float* dinv = B + (size_t)N_NODES * 128;   // N
    float* st   = dinv + N_NODES;              // 768 floats of stats
    float* sc1  = st + 256;  float* sh1  = st + 384;
    float* sc2  = st + 640;  float* sh2  = st + 704;
    int* cnt      = (int*)(st + 768);          // N
    int* row_ptr  = cnt + N_NODES;             // N+1
    int* cursor   = row_ptr + N_NODES + 1;     // N
    int* csr_src  = cursor + N_NODES;          // E
    int* partials = csr_src + N_EDGES;         // NB_SCAN
    unsigned short* wb = (unsigned short*)(partials + NB_SCAN);  // 128*192 bf16 tiled
    unsigned short* w2h = wb + (size_t)F_HID * KP;               // 128*64 bf16
    unsigned short* w2l = w2h + (size_t)F_HID * F_OUT;           // 128*64 bf16

    // BN partials, 16B aligned
    size_t off = (size_t)((char*)(w2l + F_HID * F_OUT) - (char*)d_ws);
    off = (off + 15) & ~(size_t)15;
    float* ps1  = (float*)((char*)d_ws + off);   // NBLK*128
    float* ps1q = ps1 + (size_t)NBLK * 128;      // NBLK*128
    float* ps2  = ps1q + (size_t)NBLK * 128;     // NBLK*64
    float* ps2q = ps2 + (size_t)NBLK * 64;       // NBLK*64

    hipMemsetAsync(st, 0, (768 + N_NODES) * sizeof(float), stream);

    const int EB = (N_EDGES + 255) / 256;
    const int GB64 = (N_NODES + 63) / 64;

    // CSR build + dinv (+ weight tiling kernels, independent)
    k_count<<<EB, 256, 0, stream>>>(dst, cnt);
    k_cvt_w<<<(F_HID * KP + 255) / 256, 256, 0, stream>>>(W1, wb);
    k_cvt_w2<<<(F_HID * F_OUT + 255) / 256, 256, 0, stream>>>(W2, w2h, w2l);
    k_scanA<<<NB_SCAN, 256, 0, stream>>>(cnt, partials);
    k_scanB<<<1, 1024, 0, stream>>>(partials, row_ptr);
    k_scanC<<<NB_SCAN, 256, 0, stream>>>(cnt, partials, row_ptr, cursor, dinv);
    k_scatter<<<EB, 256, 0, stream>>>(src, dst, cursor, csr_src);

    // layer 1 (fused cvt+MFMA GEMM, x read direct)
    k_mfma1<<<GB128C, 256, 0, stream>>>(x, wb, dinv, A);
    k_aggr<128, 32, 8><<<NBLK, 256, 0, stream>>>(A, row_ptr, csr_src, dinv, B, ps1, ps1q);
    k_bn_fin<128><<<1, 1024, 0, stream>>>(ps1, ps1q, g1, be1, sc1, sh1);

    // layer 2 (BN1+relu fused into split-bf16 MFMA GEMM2)
    k_mfma2<<<GB128C, 256, 0, stream>>>(B, sc1, sh1, w2h, w2l, dinv, A);
    k_aggr<64, 16, 16><<<NBLK, 256, 0, stream>>>(A, row_ptr, csr_src, dinv, B, ps2, ps2q);
    k_bn_fin<64><<<1, 1024, 0, stream>>>(ps2, ps2q, g2, be2, sc2, sh2);

    // BN2-apply + MLP head, writes both outputs
    k_final<<<GB64, 256, 0, stream>>>(B, sc2, sh2, Wp1, bp1, Wp2, bp2, (float*)d_out);
}

// Round 12
// 517.279 us; speedup vs baseline: 1.3185x; 1.3185x over previous
//
#include <hip/hip_runtime.h>
#include <hip/hip_bf16.h>

#define N_NODES 203769
#define N_EDGES 234355
#define F_IN    165
#define F_HID   128
#define F_OUT   64
#define BN_EPS  1e-5f
#define NB_SCAN 796   // ceil(N_NODES/256)
#define KP      192   // K padded to 6*32 for mfma_16x16x32
#define NBLK    4096  // aggregation grid
#define RBLK    32    // stage-1 reduction blocks (each handles NBLK/RBLK rows)
#define GB128C  1593  // ceil(N_NODES/128)

typedef short bf16x8 __attribute__((ext_vector_type(8)));
typedef unsigned short u16x8 __attribute__((ext_vector_type(8)));
typedef float f32x4 __attribute__((ext_vector_type(4)));
typedef float f32x4u __attribute__((ext_vector_type(4), aligned(4)));  // 4B-aligned vec load

__device__ __forceinline__ unsigned short f2bf(float f) {
    unsigned int u = __builtin_bit_cast(unsigned int, f);
    u += 0x7fffu + ((u >> 16) & 1u);   // RNE
    return (unsigned short)(u >> 16);
}
__device__ __forceinline__ float bf2f(unsigned short h) {
    unsigned int u = ((unsigned int)h) << 16;
    return __builtin_bit_cast(float, u);
}

// ---------------------------------------------------------------------------
// CSR build
// ---------------------------------------------------------------------------
__global__ void k_count(const int* __restrict__ dst, int* __restrict__ cnt) {
    int e = blockIdx.x * 256 + threadIdx.x;
    if (e < N_EDGES) atomicAdd(&cnt[dst[e]], 1);
}

__global__ __launch_bounds__(256) void k_scanA(const int* __restrict__ cnt,
                                               int* __restrict__ partials) {
    __shared__ int sm[256];
    int t = threadIdx.x;
    int i = blockIdx.x * 256 + t;
    int v = (i < N_NODES) ? cnt[i] : 0;
    sm[t] = v;
    __syncthreads();
    for (int off = 128; off > 0; off >>= 1) {
        if (t < off) sm[t] += sm[t + off];
        __syncthreads();
    }
    if (t == 0) partials[blockIdx.x] = sm[0];
}

__global__ __launch_bounds__(1024) void k_scanB(int* __restrict__ partials,
                                                int* __restrict__ row_ptr) {
    __shared__ int sm[1024];
    int t = threadIdx.x;
    int v = (t < NB_SCAN) ? partials[t] : 0;
    sm[t] = v;
    __syncthreads();
    for (int off = 1; off < 1024; off <<= 1) {
        int add = (t >= off) ? sm[t - off] : 0;
        __syncthreads();
        sm[t] += add;
        __syncthreads();
    }
    if (t < NB_SCAN) partials[t] = sm[t] - v;   // exclusive
    if (t == NB_SCAN - 1) row_ptr[N_NODES] = sm[t];  // = E
}

__global__ __launch_bounds__(256) void k_scanC(const int* __restrict__ cnt,
                                               const int* __restrict__ partials,
                                               int* __restrict__ row_ptr,
                                               int* __restrict__ cursor,
                                               float* __restrict__ dinv) {
    __shared__ int sm[256];
    int t = threadIdx.x;
    int i = blockIdx.x * 256 + t;
    int v = (i < N_NODES) ? cnt[i] : 0;
    sm[t] = v;
    __syncthreads();
    for (int off = 1; off < 256; off <<= 1) {
        int add = (t >= off) ? sm[t - off] : 0;
        __syncthreads();
        sm[t] += add;
        __syncthreads();
    }
    if (i < N_NODES) {
        int p = partials[blockIdx.x] + sm[t] - v;  // exclusive prefix
        row_ptr[i] = p;
        cursor[i] = p;
        dinv[i] = rsqrtf(1.0f + (float)v);  // +1 self loop
    }
}

__global__ void k_scatter(const int* __restrict__ src, const int* __restrict__ dst,
                          int* __restrict__ cursor, int* __restrict__ csr_src) {
    int e = blockIdx.x * 256 + threadIdx.x;
    if (e < N_EDGES) {
        int pos = atomicAdd(&cursor[dst[e]], 1);
        csr_src[pos] = src[e];
    }
}

// ---------------------------------------------------------------------------
// W1 -> bf16, MFMA-fragment-tiled.
// ---------------------------------------------------------------------------
__global__ void k_cvt_w(const float* __restrict__ W1, unsigned short* __restrict__ wb) {
    int i = blockIdx.x * 256 + threadIdx.x;
    if (i < F_HID * KP) {
        int n = i / KP, k = i - n * KP;
        float v = (k < F_IN) ? W1[k * F_HID + n] : 0.0f;
        int ng = n >> 4, l16 = n & 15, kb = k >> 5, quad = (k >> 3) & 3, j = k & 7;
        wb[((((size_t)ng * 6 + kb) * 4 + quad) * 16 + l16) * 8 + j] = f2bf(v);
    }
}

// ---------------------------------------------------------------------------
// W2 -> split bf16 (hi + lo), MFMA-fragment-tiled.
// ---------------------------------------------------------------------------
__global__ void k_cvt_w2(const float* __restrict__ W2,
                         unsigned short* __restrict__ w2h,
                         unsigned short* __restrict__ w2l) {
    int i = blockIdx.x * 256 + threadIdx.x;
    if (i < F_HID * F_OUT) {
        int k = i / F_OUT, n = i - k * F_OUT;
        float v = W2[i];
        unsigned short h = f2bf(v);
        float lo = v - bf2f(h);
        int ng = n >> 4, l16 = n & 15, kb = k >> 5, quad = (k >> 3) & 3, j = k & 7;
        size_t idx = ((((size_t)ng * 4 + kb) * 4 + quad) * 16 + l16) * 8 + j;
        w2h[idx] = h;
        w2l[idx] = f2bf(lo);
    }
}

// ---------------------------------------------------------------------------
// GEMM1: h1s[N,128] = (x @ W1) * dinv[row], NO LDS / NO BARRIERS, direct x.
// ---------------------------------------------------------------------------
__global__ __launch_bounds__(256) void k_mfma1(const float* __restrict__ x,
                                               const unsigned short* __restrict__ wb,
                                               const float* __restrict__ dinv,
                                               float* __restrict__ h1s) {
    const int t = threadIdx.x;
    const int wv = t >> 6;
    const int lane = t & 63;
    const int l16 = lane & 15;
    const int quad = lane >> 4;
    const int rg0 = blockIdx.x * 8 + wv * 2;
    const int lq = quad * 16 + l16;

    f32x4 acc[2][8];
#pragma unroll
    for (int mt = 0; mt < 2; mt++)
#pragma unroll
        for (int nt = 0; nt < 8; nt++)
            acc[mt][nt] = (f32x4){0.0f, 0.0f, 0.0f, 0.0f};

#pragma unroll
    for (int kb = 0; kb < 6; kb++) {
        const int k0 = kb * 32 + quad * 8;
        bf16x8 a[2], b[8];
#pragma unroll
        for (int mt = 0; mt < 2; mt++) {
            int row = (rg0 + mt) * 16 + l16;
            u16x8 u;
            if (row < N_NODES) {
                const float* rp = x + (size_t)row * F_IN + k0;
                if (kb < 5) {                 // k0+8 <= 160 <= F_IN: full vec
                    f32x4u v0 = *(const f32x4u*)rp;
                    f32x4u v1 = *(const f32x4u*)(rp + 4);
                    u[0] = f2bf(v0[0]); u[1] = f2bf(v0[1]);
                    u[2] = f2bf(v0[2]); u[3] = f2bf(v0[3]);
                    u[4] = f2bf(v1[0]); u[5] = f2bf(v1[1]);
                    u[6] = f2bf(v1[2]); u[7] = f2bf(v1[3]);
                } else {                       // padded tail, guarded scalar
#pragma unroll
                    for (int j = 0; j < 8; j++) {
                        int k = k0 + j;
                        u[j] = (k < F_IN) ? f2bf(rp[j]) : (unsigned short)0;
                    }
                }
            } else {
#pragma unroll
                for (int j = 0; j < 8; j++) u[j] = 0;
            }
            a[mt] = __builtin_bit_cast(bf16x8, u);
        }
#pragma unroll
        for (int nt = 0; nt < 8; nt++)
            b[nt] = *(const bf16x8*)&wb[(((size_t)nt * 6 + kb) * 64 + lq) * 8];
#pragma unroll
        for (int mt = 0; mt < 2; mt++)
#pragma unroll
            for (int nt = 0; nt < 8; nt++)
                acc[mt][nt] = __builtin_amdgcn_mfma_f32_16x16x32_bf16(
                    a[mt], b[nt], acc[mt][nt], 0, 0, 0);
    }

    // epilogue: C/D col = lane&15, row = quad*4 + reg; scale by dinv[row]
#pragma unroll
    for (int mt = 0; mt < 2; mt++) {
#pragma unroll
        for (int rgi = 0; rgi < 4; rgi++) {
            int grow = (rg0 + mt) * 16 + quad * 4 + rgi;
            if (grow < N_NODES) {
                float dv = dinv[grow];
                float* orow = h1s + (size_t)grow * F_HID + l16;
#pragma unroll
                for (int nt = 0; nt < 8; nt++)
                    orow[nt * 16] = acc[mt][nt][rgi] * dv;
            }
        }
    }
}

// ---------------------------------------------------------------------------
// GEMM2: h2s[N,64] = (relu(bn1(out1)) @ W2) * dinv, split-bf16 MFMA.
// ---------------------------------------------------------------------------
__global__ __launch_bounds__(256) void k_mfma2(const float* __restrict__ out1,
                                               const float* __restrict__ sc1,
                                               const float* __restrict__ sh1,
                                               const unsigned short* __restrict__ w2h,
                                               const unsigned short* __restrict__ w2l,
                                               const float* __restrict__ dinv,
                                               float* __restrict__ h2s) {
    const int t = threadIdx.x;
    const int wv = t >> 6;
    const int lane = t & 63;
    const int l16 = lane & 15;
    const int quad = lane >> 4;
    const int rg0 = blockIdx.x * 8 + wv * 2;
    const int lq = quad * 16 + l16;

    f32x4 acc[2][4];
#pragma unroll
    for (int mt = 0; mt < 2; mt++)
#pragma unroll
        for (int nt = 0; nt < 4; nt++)
            acc[mt][nt] = (f32x4){0.0f, 0.0f, 0.0f, 0.0f};

#pragma unroll
    for (int kb = 0; kb < 4; kb++) {
        const int k0 = kb * 32 + quad * 8;
        float4 sA = *(const float4*)&sc1[k0];
        float4 sB = *(const float4*)&sc1[k0 + 4];
        float4 hA = *(const float4*)&sh1[k0];
        float4 hB = *(const float4*)&sh1[k0 + 4];
        float sv[8] = {sA.x, sA.y, sA.z, sA.w, sB.x, sB.y, sB.z, sB.w};
        float hv[8] = {hA.x, hA.y, hA.z, hA.w, hB.x, hB.y, hB.z, hB.w};

        bf16x8 bh[4], bl[4];
#pragma unroll
        for (int nt = 0; nt < 4; nt++) {
            size_t u = ((((size_t)nt * 4 + kb) * 64) + lq) * 8;
            bh[nt] = *(const bf16x8*)&w2h[u];
            bl[nt] = *(const bf16x8*)&w2l[u];
        }

        bf16x8 ah[2], al[2];
#pragma unroll
        for (int mt = 0; mt < 2; mt++) {
            int row = (rg0 + mt) * 16 + l16;
            float v[8];
            if (row < N_NODES) {
                const float* rp = out1 + (size_t)row * F_HID + k0;
                float4 v0 = *(const float4*)rp;
                float4 v1 = *(const float4*)(rp + 4);
                v[0] = v0.x; v[1] = v0.y; v[2] = v0.z; v[3] = v0.w;
                v[4] = v1.x; v[5] = v1.y; v[6] = v1.z; v[7] = v1.w;
            } else {
#pragma unroll
                for (int j = 0; j < 8; j++) v[j] = 0.0f;
            }
            u16x8 uh, ul;
#pragma unroll
            for (int j = 0; j < 8; j++) {
                float f = fmaxf(fmaf(v[j], sv[j], hv[j]), 0.0f);
                unsigned short hb = f2bf(f);
                uh[j] = hb;
                ul[j] = f2bf(f - bf2f(hb));
            }
            ah[mt] = __builtin_bit_cast(bf16x8, uh);
            al[mt] = __builtin_bit_cast(bf16x8, ul);
        }

#pragma unroll
        for (int mt = 0; mt < 2; mt++)
#pragma unroll
            for (int nt = 0; nt < 4; nt++) {
                acc[mt][nt] = __builtin_amdgcn_mfma_f32_16x16x32_bf16(
                    ah[mt], bh[nt], acc[mt][nt], 0, 0, 0);
                acc[mt][nt] = __builtin_amdgcn_mfma_f32_16x16x32_bf16(
                    al[mt], bh[nt], acc[mt][nt], 0, 0, 0);
                acc[mt][nt] = __builtin_amdgcn_mfma_f32_16x16x32_bf16(
                    ah[mt], bl[nt], acc[mt][nt], 0, 0, 0);
            }
    }

#pragma unroll
    for (int mt = 0; mt < 2; mt++) {
#pragma unroll
        for (int rgi = 0; rgi < 4; rgi++) {
            int grow = (rg0 + mt) * 16 + quad * 4 + rgi;
            if (grow < N_NODES) {
                float dv = dinv[grow];
                float* orow = h2s + (size_t)grow * F_OUT + l16;
#pragma unroll
                for (int nt = 0; nt < 4; nt++)
                    orow[nt * 16] = acc[mt][nt][rgi] * dv;
            }
        }
    }
}

// ---------------------------------------------------------------------------
// Aggregation: single-pass CSR chase, BN stats as per-block partials.
// ---------------------------------------------------------------------------
template <int C, int TPN, int NPB>
__global__ __launch_bounds__(256) void k_aggr(const float* __restrict__ hs,
                                              const int* __restrict__ row_ptr,
                                              const int* __restrict__ csr_src,
                                              const float* __restrict__ dinv,
                                              float* __restrict__ out,
                                              float* __restrict__ psum,
                                              float* __restrict__ psq) {
    const int t = threadIdx.x;
    const int q = t & (TPN - 1);
    const int slot = t / TPN;
    float s0 = 0, s1 = 0, s2 = 0, s3 = 0;
    float q0 = 0, q1 = 0, q2 = 0, q3 = 0;

    for (int node = blockIdx.x * NPB + slot; node < N_NODES;
         node += gridDim.x * NPB) {
        int beg = row_ptr[node];
        int end = row_ptr[node + 1];
        float4 acc = *(const float4*)&hs[(size_t)node * C + q * 4];
        for (int e = beg; e < end; e++) {
            int s = csr_src[e];
            float4 v = *(const float4*)&hs[(size_t)s * C + q * 4];
            acc.x += v.x; acc.y += v.y; acc.z += v.z; acc.w += v.w;
        }
        float dv = dinv[node];
        acc.x *= dv; acc.y *= dv; acc.z *= dv; acc.w *= dv;
        *(float4*)&out[(size_t)node * C + q * 4] = acc;
        s0 += acc.x; s1 += acc.y; s2 += acc.z; s3 += acc.w;
        q0 = fmaf(acc.x, acc.x, q0); q1 = fmaf(acc.y, acc.y, q1);
        q2 = fmaf(acc.z, acc.z, q2); q3 = fmaf(acc.w, acc.w, q3);
    }

    __shared__ float sm[256 * 4];
    __shared__ float sq[256 * 4];
    sm[t * 4 + 0] = s0; sm[t * 4 + 1] = s1; sm[t * 4 + 2] = s2; sm[t * 4 + 3] = s3;
    sq[t * 4 + 0] = q0; sq[t * 4 + 1] = q1; sq[t * 4 + 2] = q2; sq[t * 4 + 3] = q3;
    __syncthreads();
    if (t < TPN) {
#pragma unroll
        for (int sl = 1; sl < NPB; sl++) {
            int u = (sl * TPN + t) * 4;
            s0 += sm[u + 0]; s1 += sm[u + 1]; s2 += sm[u + 2]; s3 += sm[u + 3];
            q0 += sq[u + 0]; q1 += sq[u + 1]; q2 += sq[u + 2]; q3 += sq[u + 3];
        }
        float4 o1 = {s0, s1, s2, s3};
        float4 o2 = {q0, q1, q2, q3};
        *(float4*)&psum[(size_t)blockIdx.x * C + t * 4] = o1;
        *(float4*)&psq [(size_t)blockIdx.x * C + t * 4] = o2;
    }
}

// ---------------------------------------------------------------------------
// BN partial reduction, stage 1 (R13): RBLK blocks x 1024 thr; each block
// reduces NBLK/RBLK rows of psum/psq -> one row in ss/ssq.
// R11 post-mortem: single-block k_bn_fin scaled with NBLK (152us @4096,
// 0.17% BW, one CU). Two-stage makes reduction cost NBLK-independent.
// ---------------------------------------------------------------------------
template <int C>
__global__ __launch_bounds__(1024) void k_bn_red(const float* __restrict__ psum,
                                                 const float* __restrict__ psq,
                                                 float* __restrict__ ss,
                                                 float* __restrict__ ssq) {
    const int t = threadIdx.x;
    const int c = t & (C - 1);
    const int gg = t / C;              // 0..G-1
    const int G = 1024 / C;
    const int ROWS = NBLK / RBLK;      // rows per block
    const int BPG = ROWS / G;          // rows per group
    const int r0 = blockIdx.x * ROWS + gg * BPG;
    float s = 0.0f, sq_ = 0.0f;
    for (int i = 0; i < BPG; i++) {
        int b = r0 + i;
        s   += psum[(size_t)b * C + c];
        sq_ += psq [(size_t)b * C + c];
    }
    __shared__ float sm[1024];
    __shared__ float s2[1024];
    sm[t] = s;
    s2[t] = sq_;
    __syncthreads();
    for (int off = G / 2; off > 0; off >>= 1) {
        if (gg < off) {
            sm[t] += sm[t + off * C];
            s2[t] += s2[t + off * C];
        }
        __syncthreads();
    }
    if (gg == 0) {
        ss [(size_t)blockIdx.x * C + c] = sm[c];
        ssq[(size_t)blockIdx.x * C + c] = s2[c];
    }
}

// ---------------------------------------------------------------------------
// BN partial reduction, stage 2: 1 block reduces RBLK rows -> scale/shift.
// ---------------------------------------------------------------------------
template <int C>
__global__ __launch_bounds__(1024) void k_bn_fin(const float* __restrict__ ss,
                                                 const float* __restrict__ ssq,
                                                 const float* __restrict__ g,
                                                 const float* __restrict__ be,
                                                 float* __restrict__ sc,
                                                 float* __restrict__ sh) {
    const int t = threadIdx.x;
    const int c = t & (C - 1);
    const int gg = t / C;          // 0..G-1
    const int G = 1024 / C;
    const int BPG = RBLK / G;      // 4 (C=128) or 2 (C=64)
    float s = 0.0f, sq_ = 0.0f;
    for (int i = 0; i < BPG; i++) {
        int b = gg * BPG + i;
        s   += ss [(size_t)b * C + c];
        sq_ += ssq[(size_t)b * C + c];
    }
    __shared__ float sm[1024];
    __shared__ float s2[1024];
    sm[t] = s;
    s2[t] = sq_;
    __syncthreads();
    for (int off = G / 2; off > 0; off >>= 1) {
        if (gg < off) {
            sm[t] += sm[t + off * C];
            s2[t] += s2[t + off * C];
        }
        __syncthreads();
    }
    if (gg == 0) {
        const float invn = 1.0f / (float)N_NODES;
        float mean = sm[c] * invn;
        float var = s2[c] * invn - mean * mean;
        float rstd = rsqrtf(var + BN_EPS);
        float scale = g[c] * rstd;
        sc[c] = scale;
        sh[c] = fmaf(-mean, scale, be[c]);
    }
}

// ---------------------------------------------------------------------------
// Final: hf = bn2(out2) -> d_out; z = relu(hf@Wp1+bp1)@Wp2+bp2
// ---------------------------------------------------------------------------
__global__ __launch_bounds__(256) void k_final(const float* __restrict__ out2,
                                               const float* __restrict__ sc2,
                                               const float* __restrict__ sh2,
                                               const float* __restrict__ Wp1,
                                               const float* __restrict__ bp1,
                                               const float* __restrict__ Wp2,
                                               const float* __restrict__ bp2,
                                               float* __restrict__ out) {
    __shared__ float hs[64 * 68];   // 17.4 KB
    __shared__ float as_[64 * 68];  // 17.4 KB
    const int row0 = blockIdx.x * 64;
    const int t = threadIdx.x;

    {
        const float4* src = (const float4*)out2;
        float4* dsth = (float4*)out;
#pragma unroll
        for (int i = 0; i < 4; i++) {
            int f4 = t + i * 256;         // 0..1023
            int r = f4 >> 4;
            int c4 = f4 & 15;
            int grow = row0 + r;
            float4 v = {0, 0, 0, 0};
            if (grow < N_NODES) v = src[(size_t)grow * 16 + c4];
            int c = c4 * 4;
            v.x = fmaf(v.x, sc2[c + 0], sh2[c + 0]);
            v.y = fmaf(v.y, sc2[c + 1], sh2[c + 1]);
            v.z = fmaf(v.z, sc2[c + 2], sh2[c + 2]);
            v.w = fmaf(v.w, sc2[c + 3], sh2[c + 3]);
            if (grow < N_NODES) dsth[(size_t)grow * 16 + c4] = v;
            *(float4*)&hs[r * 68 + c] = v;
        }
    }
    __syncthreads();

    const int c0 = (t & 15) * 4;
    const int r0 = (t >> 4) * 4;

    // GEMM A: a = relu(hs @ Wp1 + bp1)
    {
        float acc[4][4];
#pragma unroll
        for (int r = 0; r < 4; r++)
#pragma unroll
            for (int c = 0; c < 4; c++) acc[r][c] = 0.0f;
#pragma unroll 2
        for (int k4 = 0; k4 < 64; k4 += 4) {
            float4 xv[4];
#pragma unroll
            for (int r = 0; r < 4; r++)
                xv[r] = *(const float4*)&hs[(r0 + r) * 68 + k4];
            float4 w[4];
#pragma unroll
            for (int j = 0; j < 4; j++)
                w[j] = *(const float4*)&Wp1[(k4 + j) * 64 + c0];
#pragma unroll
            for (int r = 0; r < 4; r++) {
                const float xr[4] = {xv[r].x, xv[r].y, xv[r].z, xv[r].w};
#pragma unroll
                for (int j = 0; j < 4; j++) {
                    acc[r][0] = fmaf(xr[j], w[j].x, acc[r][0]);
                    acc[r][1] = fmaf(xr[j], w[j].y, acc[r][1]);
                    acc[r][2] = fmaf(xr[j], w[j].z, acc[r][2]);
                    acc[r][3] = fmaf(xr[j], w[j].w, acc[r][3]);
                }
            }
        }
        float4 b = *(const float4*)&bp1[c0];
#pragma unroll
        for (int r = 0; r < 4; r++) {
            float4 o = {fmaxf(acc[r][0] + b.x, 0.0f), fmaxf(acc[r][1] + b.y, 0.0f),
                        fmaxf(acc[r][2] + b.z, 0.0f), fmaxf(acc[r][3] + b.w, 0.0f)};
            *(float4*)&as_[(r0 + r) * 68 + c0] = o;
        }
    }
    __syncthreads();

    // GEMM B: z = a @ Wp2 + bp2
    {
        float acc[4][4];
#pragma unroll
        for (int r = 0; r < 4; r++)
#pragma unroll
            for (int c = 0; c < 4; c++) acc[r][c] = 0.0f;
#pragma unroll 2
        for (int k4 = 0; k4 < 64; k4 += 4) {
            float4 xv[4];
#pragma unroll
            for (int r = 0; r < 4; r++)
                xv[r] = *(const float4*)&as_[(r0 + r) * 68 + k4];
            float4 w[4];
#pragma unroll
            for (int j = 0; j < 4; j++)
                w[j] = *(const float4*)&Wp2[(k4 + j) * 64 + c0];
#pragma unroll
            for (int r = 0; r < 4; r++) {
                const float xr[4] = {xv[r].x, xv[r].y, xv[r].z, xv[r].w};
#pragma unroll
                for (int j = 0; j < 4; j++) {
                    acc[r][0] = fmaf(xr[j], w[j].x, acc[r][0]);
                    acc[r][1] = fmaf(xr[j], w[j].y, acc[r][1]);
                    acc[r][2] = fmaf(xr[j], w[j].z, acc[r][2]);
                    acc[r][3] = fmaf(xr[j], w[j].w, acc[r][3]);
                }
            }
        }
        float4 b = *(const float4*)&bp2[c0];
        float* zout = out + (size_t)N_NODES * 64;
#pragma unroll
        for (int r = 0; r < 4; r++) {
            int row = row0 + r0 + r;
            if (row < N_NODES) {
                float4 o = {acc[r][0] + b.x, acc[r][1] + b.y,
                            acc[r][2] + b.z, acc[r][3] + b.w};
                *(float4*)&zout[(size_t)row * 64 + c0] = o;
            }
        }
    }
}

// ---------------------------------------------------------------------------
// launch
// ---------------------------------------------------------------------------
extern "C" void kernel_launch(void* const* d_in, const int* in_sizes, int n_in,
                              void* d_out, int out_size, void* d_ws, size_t ws_size,
                              hipStream_t stream) {
    const float* x   = (const float*)d_in[0];
    const int*   ei  = (const int*)d_in[1];
    const float* W1  = (const float*)d_in[2];
    // b1 (d_in[3]) skipped: column-constant shift cancelled by BN1
    const float* g1  = (const float*)d_in[4];
    const float* be1 = (const float*)d_in[5];
    const float* W2  = (const float*)d_in[6];
    // b2 (d_in[7]) skipped: cancelled by BN2
    const float* g2  = (const float*)d_in[8];
    const float* be2 = (const float*)d_in[9];
    const float* Wp1 = (const float*)d_in[10];
    const float* bp1 = (const float*)d_in[11];
    const float* Wp2 = (const float*)d_in[12];
    const float* bp2 = (const float*)d_in[13];

    const int* src = ei;            // edge_index[0]
    const int* dst = ei + N_EDGES;  // edge_index[1]

    float* ws = (float*)d_ws;
    float* A    = ws;                          // h1s (N*128) / h2s (N*64)
    float* B    = A + (size_t)N_NODES * 128;   // out1 (N*128) / out2 (N*64)
    float* dinv = B + (size_t)N_NODES * 128;   // N
    float* st   = dinv + N_NODES;              // 768 floats of stats
    float* sc1  = st + 256;  float* sh1  = st + 384;
    float* sc2  = st + 640;  float* sh2  = st + 704;
    int* cnt      = (int*)(st + 768);          // N
    int* row_ptr  = cnt + N_NODES;             // N+1
    int* cursor   = row_ptr + N_NODES + 1;     // N
    int* csr_src  = cursor + N_NODES;          // E
    int* partials = csr_src + N_EDGES;         // NB_SCAN
    unsigned short* wb = (unsigned short*)(partials + NB_SCAN);  // 128*192 bf16 tiled
    unsigned short* w2h = wb + (size_t)F_HID * KP;               // 128*64 bf16
    unsigned short* w2l = w2h + (size_t)F_HID * F_OUT;           // 128*64 bf16

    // BN partials + stage-1 outputs, 16B aligned
    size_t off = (size_t)((char*)(w2l + F_HID * F_OUT) - (char*)d_ws);
    off = (off + 15) & ~(size_t)15;
    float* ps1  = (float*)((char*)d_ws + off);   // NBLK*128
    float* ps1q = ps1 + (size_t)NBLK * 128;      // NBLK*128
    float* ps2  = ps1q + (size_t)NBLK * 128;     // NBLK*64
    float* ps2q = ps2 + (size_t)NBLK * 64;       // NBLK*64
    float* ss1  = ps2q + (size_t)NBLK * 64;      // RBLK*128
    float* ss1q = ss1 + (size_t)RBLK * 128;      // RBLK*128
    float* ss2  = ss1q + (size_t)RBLK * 128;     // RBLK*64
    float* ss2q = ss2 + (size_t)RBLK * 64;       // RBLK*64

    hipMemsetAsync(st, 0, (768 + N_NODES) * sizeof(float), stream);

    const int EB = (N_EDGES + 255) / 256;
    const int GB64 = (N_NODES + 63) / 64;

    // CSR build + dinv (+ weight tiling kernels, independent)
    k_count<<<EB, 256, 0, stream>>>(dst, cnt);
    k_cvt_w<<<(F_HID * KP + 255) / 256, 256, 0, stream>>>(W1, wb);
    k_cvt_w2<<<(F_HID * F_OUT + 255) / 256, 256, 0, stream>>>(W2, w2h, w2l);
    k_scanA<<<NB_SCAN, 256, 0, stream>>>(cnt, partials);
    k_scanB<<<1, 1024, 0, stream>>>(partials, row_ptr);
    k_scanC<<<NB_SCAN, 256, 0, stream>>>(cnt, partials, row_ptr, cursor, dinv);
    k_scatter<<<EB, 256, 0, stream>>>(src, dst, cursor, csr_src);

    // layer 1 (fused cvt+MFMA GEMM, x read direct)
    k_mfma1<<<GB128C, 256, 0, stream>>>(x, wb, dinv, A);
    k_aggr<128, 32, 8><<<NBLK, 256, 0, stream>>>(A, row_ptr, csr_src, dinv, B, ps1, ps1q);
    k_bn_red<128><<<RBLK, 1024, 0, stream>>>(ps1, ps1q, ss1, ss1q);
    k_bn_fin<128><<<1, 1024, 0, stream>>>(ss1, ss1q, g1, be1, sc1, sh1);

    // layer 2 (BN1+relu fused into split-bf16 MFMA GEMM2)
    k_mfma2<<<GB128C, 256, 0, stream>>>(B, sc1, sh1, w2h, w2l, dinv, A);
    k_aggr<64, 16, 16><<<NBLK, 256, 0, stream>>>(A, row_ptr, csr_src, dinv, B, ps2, ps2q);
    k_bn_red<64><<<RBLK, 1024, 0, stream>>>(ps2, ps2q, ss2, ss2q);
    k_bn_fin<64><<<1, 1024, 0, stream>>>(ss2, ss2q, g2, be2, sc2, sh2);

    // BN2-apply + MLP head, writes both outputs
    k_final<<<GB64, 256, 0, stream>>>(B, sc2, sh2, Wp1, bp1, Wp2, bp2, (float*)d_out);
}

// Round 13
// 512.161 us; speedup vs baseline: 1.3317x; 1.0100x over previous
//
#include <hip/hip_runtime.h>
#include <hip/hip_bf16.h>

#define N_NODES 203769
#define N_EDGES 234355
#define F_IN    165
#define F_HID   128
#define F_OUT   64
#define BN_EPS  1e-5f
#define NB_SCAN 796   // ceil(N_NODES/256)
#define KP      192   // K padded to 6*32 for mfma_16x16x32
#define NBLK    4096  // aggregation grid
#define RBLK    32    // stage-1 reduction blocks
#define GB64C   3184  // ceil(N_NODES/64): k_mfma1 grid (4 waves x 1 rowgroup)
#define GB128C  1593  // ceil(N_NODES/128): k_mfma2 grid

typedef short bf16x8 __attribute__((ext_vector_type(8)));
typedef unsigned short u16x8 __attribute__((ext_vector_type(8)));
typedef float f32x4 __attribute__((ext_vector_type(4)));
typedef float f32x4u __attribute__((ext_vector_type(4), aligned(4)));  // 4B-aligned vec load

__device__ __forceinline__ unsigned short f2bf(float f) {
    unsigned int u = __builtin_bit_cast(unsigned int, f);
    u += 0x7fffu + ((u >> 16) & 1u);   // RNE
    return (unsigned short)(u >> 16);
}
__device__ __forceinline__ float bf2f(unsigned short h) {
    unsigned int u = ((unsigned int)h) << 16;
    return __builtin_bit_cast(float, u);
}

// ---------------------------------------------------------------------------
// CSR build
// ---------------------------------------------------------------------------
__global__ void k_count(const int* __restrict__ dst, int* __restrict__ cnt) {
    int e = blockIdx.x * 256 + threadIdx.x;
    if (e < N_EDGES) atomicAdd(&cnt[dst[e]], 1);
}

__global__ __launch_bounds__(256) void k_scanA(const int* __restrict__ cnt,
                                               int* __restrict__ partials) {
    __shared__ int sm[256];
    int t = threadIdx.x;
    int i = blockIdx.x * 256 + t;
    int v = (i < N_NODES) ? cnt[i] : 0;
    sm[t] = v;
    __syncthreads();
    for (int off = 128; off > 0; off >>= 1) {
        if (t < off) sm[t] += sm[t + off];
        __syncthreads();
    }
    if (t == 0) partials[blockIdx.x] = sm[0];
}

__global__ __launch_bounds__(1024) void k_scanB(int* __restrict__ partials,
                                                int* __restrict__ row_ptr) {
    __shared__ int sm[1024];
    int t = threadIdx.x;
    int v = (t < NB_SCAN) ? partials[t] : 0;
    sm[t] = v;
    __syncthreads();
    for (int off = 1; off < 1024; off <<= 1) {
        int add = (t >= off) ? sm[t - off] : 0;
        __syncthreads();
        sm[t] += add;
        __syncthreads();
    }
    if (t < NB_SCAN) partials[t] = sm[t] - v;   // exclusive
    if (t == NB_SCAN - 1) row_ptr[N_NODES] = sm[t];  // = E
}

__global__ __launch_bounds__(256) void k_scanC(const int* __restrict__ cnt,
                                               const int* __restrict__ partials,
                                               int* __restrict__ row_ptr,
                                               int* __restrict__ cursor,
                                               float* __restrict__ dinv) {
    __shared__ int sm[256];
    int t = threadIdx.x;
    int i = blockIdx.x * 256 + t;
    int v = (i < N_NODES) ? cnt[i] : 0;
    sm[t] = v;
    __syncthreads();
    for (int off = 1; off < 256; off <<= 1) {
        int add = (t >= off) ? sm[t - off] : 0;
        __syncthreads();
        sm[t] += add;
        __syncthreads();
    }
    if (i < N_NODES) {
        int p = partials[blockIdx.x] + sm[t] - v;  // exclusive prefix
        row_ptr[i] = p;
        cursor[i] = p;
        dinv[i] = rsqrtf(1.0f + (float)v);  // +1 self loop
    }
}

__global__ void k_scatter(const int* __restrict__ src, const int* __restrict__ dst,
                          int* __restrict__ cursor, int* __restrict__ csr_src) {
    int e = blockIdx.x * 256 + threadIdx.x;
    if (e < N_EDGES) {
        int pos = atomicAdd(&cursor[dst[e]], 1);
        csr_src[pos] = src[e];
    }
}

// ---------------------------------------------------------------------------
// W1 -> bf16, MFMA-fragment-tiled.
// ---------------------------------------------------------------------------
__global__ void k_cvt_w(const float* __restrict__ W1, unsigned short* __restrict__ wb) {
    int i = blockIdx.x * 256 + threadIdx.x;
    if (i < F_HID * KP) {
        int n = i / KP, k = i - n * KP;
        float v = (k < F_IN) ? W1[k * F_HID + n] : 0.0f;
        int ng = n >> 4, l16 = n & 15, kb = k >> 5, quad = (k >> 3) & 3, j = k & 7;
        wb[((((size_t)ng * 6 + kb) * 4 + quad) * 16 + l16) * 8 + j] = f2bf(v);
    }
}

// ---------------------------------------------------------------------------
// W2 -> split bf16 (hi + lo), MFMA-fragment-tiled.
// ---------------------------------------------------------------------------
__global__ void k_cvt_w2(const float* __restrict__ W2,
                         unsigned short* __restrict__ w2h,
                         unsigned short* __restrict__ w2l) {
    int i = blockIdx.x * 256 + threadIdx.x;
    if (i < F_HID * F_OUT) {
        int k = i / F_OUT, n = i - k * F_OUT;
        float v = W2[i];
        unsigned short h = f2bf(v);
        float lo = v - bf2f(h);
        int ng = n >> 4, l16 = n & 15, kb = k >> 5, quad = (k >> 3) & 3, j = k & 7;
        size_t idx = ((((size_t)ng * 4 + kb) * 4 + quad) * 16 + l16) * 8 + j;
        w2h[idx] = h;
        w2l[idx] = f2bf(lo);
    }
}

// ---------------------------------------------------------------------------
// GEMM1 (R14): h1s[N,128] = (x @ W1) * dinv[row], NO LDS / NO BARRIERS,
// direct x. mt=2 -> mt=1: each wave owns ONE 16-row group (acc[8] = 32 VGPR
// vs 64), grid 1593 -> 3184 blocks. R12 counters (101us @ 1.88TB/s, 3.7%
// MFMA, 25% occ) = residency-limited; halving wave grain doubles wave
// supply and cuts VGPR so more waves co-reside. Same fragment mappings,
// same x traffic (wb re-reads double but wb = 48KB L2-resident).
// ---------------------------------------------------------------------------
__global__ __launch_bounds__(256) void k_mfma1(const float* __restrict__ x,
                                               const unsigned short* __restrict__ wb,
                                               const float* __restrict__ dinv,
                                               float* __restrict__ h1s) {
    const int t = threadIdx.x;
    const int wv = t >> 6;
    const int lane = t & 63;
    const int l16 = lane & 15;
    const int quad = lane >> 4;
    const int rg = blockIdx.x * 4 + wv;       // this wave's 16-row group
    const int lq = quad * 16 + l16;
    const int row = rg * 16 + l16;            // thread's fixed source row

    f32x4 acc[8];
#pragma unroll
    for (int nt = 0; nt < 8; nt++)
        acc[nt] = (f32x4){0.0f, 0.0f, 0.0f, 0.0f};

#pragma unroll
    for (int kb = 0; kb < 6; kb++) {
        const int k0 = kb * 32 + quad * 8;
        u16x8 u;
        if (row < N_NODES) {
            const float* rp = x + (size_t)row * F_IN + k0;
            if (kb < 5) {                 // k0+8 <= 160 <= F_IN: full vec
                f32x4u v0 = *(const f32x4u*)rp;
                f32x4u v1 = *(const f32x4u*)(rp + 4);
                u[0] = f2bf(v0[0]); u[1] = f2bf(v0[1]);
                u[2] = f2bf(v0[2]); u[3] = f2bf(v0[3]);
                u[4] = f2bf(v1[0]); u[5] = f2bf(v1[1]);
                u[6] = f2bf(v1[2]); u[7] = f2bf(v1[3]);
            } else {                       // padded tail, guarded scalar
#pragma unroll
                for (int j = 0; j < 8; j++) {
                    int k = k0 + j;
                    u[j] = (k < F_IN) ? f2bf(rp[j]) : (unsigned short)0;
                }
            }
        } else {
#pragma unroll
            for (int j = 0; j < 8; j++) u[j] = 0;
        }
        bf16x8 a = __builtin_bit_cast(bf16x8, u);
        bf16x8 b[8];
#pragma unroll
        for (int nt = 0; nt < 8; nt++)
            b[nt] = *(const bf16x8*)&wb[(((size_t)nt * 6 + kb) * 64 + lq) * 8];
#pragma unroll
        for (int nt = 0; nt < 8; nt++)
            acc[nt] = __builtin_amdgcn_mfma_f32_16x16x32_bf16(a, b[nt], acc[nt], 0, 0, 0);
    }

    // epilogue: C/D col = lane&15, row = quad*4 + reg; scale by dinv[row]
#pragma unroll
    for (int rgi = 0; rgi < 4; rgi++) {
        int grow = rg * 16 + quad * 4 + rgi;
        if (grow < N_NODES) {
            float dv = dinv[grow];
            float* orow = h1s + (size_t)grow * F_HID + l16;
#pragma unroll
            for (int nt = 0; nt < 8; nt++)
                orow[nt * 16] = acc[nt][rgi] * dv;
        }
    }
}

// ---------------------------------------------------------------------------
// GEMM2: h2s[N,64] = (relu(bn1(out1)) @ W2) * dinv, split-bf16 MFMA.
// ---------------------------------------------------------------------------
__global__ __launch_bounds__(256) void k_mfma2(const float* __restrict__ out1,
                                               const float* __restrict__ sc1,
                                               const float* __restrict__ sh1,
                                               const unsigned short* __restrict__ w2h,
                                               const unsigned short* __restrict__ w2l,
                                               const float* __restrict__ dinv,
                                               float* __restrict__ h2s) {
    const int t = threadIdx.x;
    const int wv = t >> 6;
    const int lane = t & 63;
    const int l16 = lane & 15;
    const int quad = lane >> 4;
    const int rg0 = blockIdx.x * 8 + wv * 2;
    const int lq = quad * 16 + l16;

    f32x4 acc[2][4];
#pragma unroll
    for (int mt = 0; mt < 2; mt++)
#pragma unroll
        for (int nt = 0; nt < 4; nt++)
            acc[mt][nt] = (f32x4){0.0f, 0.0f, 0.0f, 0.0f};

#pragma unroll
    for (int kb = 0; kb < 4; kb++) {
        const int k0 = kb * 32 + quad * 8;
        float4 sA = *(const float4*)&sc1[k0];
        float4 sB = *(const float4*)&sc1[k0 + 4];
        float4 hA = *(const float4*)&sh1[k0];
        float4 hB = *(const float4*)&sh1[k0 + 4];
        float sv[8] = {sA.x, sA.y, sA.z, sA.w, sB.x, sB.y, sB.z, sB.w};
        float hv[8] = {hA.x, hA.y, hA.z, hA.w, hB.x, hB.y, hB.z, hB.w};

        bf16x8 bh[4], bl[4];
#pragma unroll
        for (int nt = 0; nt < 4; nt++) {
            size_t u = ((((size_t)nt * 4 + kb) * 64) + lq) * 8;
            bh[nt] = *(const bf16x8*)&w2h[u];
            bl[nt] = *(const bf16x8*)&w2l[u];
        }

        bf16x8 ah[2], al[2];
#pragma unroll
        for (int mt = 0; mt < 2; mt++) {
            int row = (rg0 + mt) * 16 + l16;
            float v[8];
            if (row < N_NODES) {
                const float* rp = out1 + (size_t)row * F_HID + k0;
                float4 v0 = *(const float4*)rp;
                float4 v1 = *(const float4*)(rp + 4);
                v[0] = v0.x; v[1] = v0.y; v[2] = v0.z; v[3] = v0.w;
                v[4] = v1.x; v[5] = v1.y; v[6] = v1.z; v[7] = v1.w;
            } else {
#pragma unroll
                for (int j = 0; j < 8; j++) v[j] = 0.0f;
            }
            u16x8 uh, ul;
#pragma unroll
            for (int j = 0; j < 8; j++) {
                float f = fmaxf(fmaf(v[j], sv[j], hv[j]), 0.0f);
                unsigned short hb = f2bf(f);
                uh[j] = hb;
                ul[j] = f2bf(f - bf2f(hb));
            }
            ah[mt] = __builtin_bit_cast(bf16x8, uh);
            al[mt] = __builtin_bit_cast(bf16x8, ul);
        }

#pragma unroll
        for (int mt = 0; mt < 2; mt++)
#pragma unroll
            for (int nt = 0; nt < 4; nt++) {
                acc[mt][nt] = __builtin_amdgcn_mfma_f32_16x16x32_bf16(
                    ah[mt], bh[nt], acc[mt][nt], 0, 0, 0);
                acc[mt][nt] = __builtin_amdgcn_mfma_f32_16x16x32_bf16(
                    al[mt], bh[nt], acc[mt][nt], 0, 0, 0);
                acc[mt][nt] = __builtin_amdgcn_mfma_f32_16x16x32_bf16(
                    ah[mt], bl[nt], acc[mt][nt], 0, 0, 0);
            }
    }

#pragma unroll
    for (int mt = 0; mt < 2; mt++) {
#pragma unroll
        for (int rgi = 0; rgi < 4; rgi++) {
            int grow = (rg0 + mt) * 16 + quad * 4 + rgi;
            if (grow < N_NODES) {
                float dv = dinv[grow];
                float* orow = h2s + (size_t)grow * F_OUT + l16;
#pragma unroll
                for (int nt = 0; nt < 4; nt++)
                    orow[nt * 16] = acc[mt][nt][rgi] * dv;
            }
        }
    }
}

// ---------------------------------------------------------------------------
// Aggregation: single-pass CSR chase, BN stats as per-block partials.
// ---------------------------------------------------------------------------
template <int C, int TPN, int NPB>
__global__ __launch_bounds__(256) void k_aggr(const float* __restrict__ hs,
                                              const int* __restrict__ row_ptr,
                                              const int* __restrict__ csr_src,
                                              const float* __restrict__ dinv,
                                              float* __restrict__ out,
                                              float* __restrict__ psum,
                                              float* __restrict__ psq) {
    const int t = threadIdx.x;
    const int q = t & (TPN - 1);
    const int slot = t / TPN;
    float s0 = 0, s1 = 0, s2 = 0, s3 = 0;
    float q0 = 0, q1 = 0, q2 = 0, q3 = 0;

    for (int node = blockIdx.x * NPB + slot; node < N_NODES;
         node += gridDim.x * NPB) {
        int beg = row_ptr[node];
        int end = row_ptr[node + 1];
        float4 acc = *(const float4*)&hs[(size_t)node * C + q * 4];
        for (int e = beg; e < end; e++) {
            int s = csr_src[e];
            float4 v = *(const float4*)&hs[(size_t)s * C + q * 4];
            acc.x += v.x; acc.y += v.y; acc.z += v.z; acc.w += v.w;
        }
        float dv = dinv[node];
        acc.x *= dv; acc.y *= dv; acc.z *= dv; acc.w *= dv;
        *(float4*)&out[(size_t)node * C + q * 4] = acc;
        s0 += acc.x; s1 += acc.y; s2 += acc.z; s3 += acc.w;
        q0 = fmaf(acc.x, acc.x, q0); q1 = fmaf(acc.y, acc.y, q1);
        q2 = fmaf(acc.z, acc.z, q2); q3 = fmaf(acc.w, acc.w, q3);
    }

    __shared__ float sm[256 * 4];
    __shared__ float sq[256 * 4];
    sm[t * 4 + 0] = s0; sm[t * 4 + 1] = s1; sm[t * 4 + 2] = s2; sm[t * 4 + 3] = s3;
    sq[t * 4 + 0] = q0; sq[t * 4 + 1] = q1; sq[t * 4 + 2] = q2; sq[t * 4 + 3] = q3;
    __syncthreads();
    if (t < TPN) {
#pragma unroll
        for (int sl = 1; sl < NPB; sl++) {
            int u = (sl * TPN + t) * 4;
            s0 += sm[u + 0]; s1 += sm[u + 1]; s2 += sm[u + 2]; s3 += sm[u + 3];
            q0 += sq[u + 0]; q1 += sq[u + 1]; q2 += sq[u + 2]; q3 += sq[u + 3];
        }
        float4 o1 = {s0, s1, s2, s3};
        float4 o2 = {q0, q1, q2, q3};
        *(float4*)&psum[(size_t)blockIdx.x * C + t * 4] = o1;
        *(float4*)&psq [(size_t)blockIdx.x * C + t * 4] = o2;
    }
}

// ---------------------------------------------------------------------------
// BN partial reduction, stage 1: RBLK blocks x 1024 thr.
// ---------------------------------------------------------------------------
template <int C>
__global__ __launch_bounds__(1024) void k_bn_red(const float* __restrict__ psum,
                                                 const float* __restrict__ psq,
                                                 float* __restrict__ ss,
                                                 float* __restrict__ ssq) {
    const int t = threadIdx.x;
    const int c = t & (C - 1);
    const int gg = t / C;              // 0..G-1
    const int G = 1024 / C;
    const int ROWS = NBLK / RBLK;      // rows per block
    const int BPG = ROWS / G;          // rows per group
    const int r0 = blockIdx.x * ROWS + gg * BPG;
    float s = 0.0f, sq_ = 0.0f;
    for (int i = 0; i < BPG; i++) {
        int b = r0 + i;
        s   += psum[(size_t)b * C + c];
        sq_ += psq [(size_t)b * C + c];
    }
    __shared__ float sm[1024];
    __shared__ float s2[1024];
    sm[t] = s;
    s2[t] = sq_;
    __syncthreads();
    for (int off = G / 2; off > 0; off >>= 1) {
        if (gg < off) {
            sm[t] += sm[t + off * C];
            s2[t] += s2[t + off * C];
        }
        __syncthreads();
    }
    if (gg == 0) {
        ss [(size_t)blockIdx.x * C + c] = sm[c];
        ssq[(size_t)blockIdx.x * C + c] = s2[c];
    }
}

// ---------------------------------------------------------------------------
// BN partial reduction, stage 2: 1 block reduces RBLK rows -> scale/shift.
// ---------------------------------------------------------------------------
template <int C>
__global__ __launch_bounds__(1024) void k_bn_fin(const float* __restrict__ ss,
                                                 const float* __restrict__ ssq,
                                                 const float* __restrict__ g,
                                                 const float* __restrict__ be,
                                                 float* __restrict__ sc,
                                                 float* __restrict__ sh) {
    const int t = threadIdx.x;
    const int c = t & (C - 1);
    const int gg = t / C;          // 0..G-1
    const int G = 1024 / C;
    const int BPG = RBLK / G;      // 4 (C=128) or 2 (C=64)
    float s = 0.0f, sq_ = 0.0f;
    for (int i = 0; i < BPG; i++) {
        int b = gg * BPG + i;
        s   += ss [(size_t)b * C + c];
        sq_ += ssq[(size_t)b * C + c];
    }
    __shared__ float sm[1024];
    __shared__ float s2[1024];
    sm[t] = s;
    s2[t] = sq_;
    __syncthreads();
    for (int off = G / 2; off > 0; off >>= 1) {
        if (gg < off) {
            sm[t] += sm[t + off * C];
            s2[t] += s2[t + off * C];
        }
        __syncthreads();
    }
    if (gg == 0) {
        const float invn = 1.0f / (float)N_NODES;
        float mean = sm[c] * invn;
        float var = s2[c] * invn - mean * mean;
        float rstd = rsqrtf(var + BN_EPS);
        float scale = g[c] * rstd;
        sc[c] = scale;
        sh[c] = fmaf(-mean, scale, be[c]);
    }
}

// ---------------------------------------------------------------------------
// Final: hf = bn2(out2) -> d_out; z = relu(hf@Wp1+bp1)@Wp2+bp2
// ---------------------------------------------------------------------------
__global__ __launch_bounds__(256) void k_final(const float* __restrict__ out2,
                                               const float* __restrict__ sc2,
                                               const float* __restrict__ sh2,
                                               const float* __restrict__ Wp1,
                                               const float* __restrict__ bp1,
                                               const float* __restrict__ Wp2,
                                               const float* __restrict__ bp2,
                                               float* __restrict__ out) {
    __shared__ float hs[64 * 68];   // 17.4 KB
    __shared__ float as_[64 * 68];  // 17.4 KB
    const int row0 = blockIdx.x * 64;
    const int t = threadIdx.x;

    {
        const float4* src = (const float4*)out2;
        float4* dsth = (float4*)out;
#pragma unroll
        for (int i = 0; i < 4; i++) {
            int f4 = t + i * 256;         // 0..1023
            int r = f4 >> 4;
            int c4 = f4 & 15;
            int grow = row0 + r;
            float4 v = {0, 0, 0, 0};
            if (grow < N_NODES) v = src[(size_t)grow * 16 + c4];
            int c = c4 * 4;
            v.x = fmaf(v.x, sc2[c + 0], sh2[c + 0]);
            v.y = fmaf(v.y, sc2[c + 1], sh2[c + 1]);
            v.z = fmaf(v.z, sc2[c + 2], sh2[c + 2]);
            v.w = fmaf(v.w, sc2[c + 3], sh2[c + 3]);
            if (grow < N_NODES) dsth[(size_t)grow * 16 + c4] = v;
            *(float4*)&hs[r * 68 + c] = v;
        }
    }
    __syncthreads();

    const int c0 = (t & 15) * 4;
    const int r0 = (t >> 4) * 4;

    // GEMM A: a = relu(hs @ Wp1 + bp1)
    {
        float acc[4][4];
#pragma unroll
        for (int r = 0; r < 4; r++)
#pragma unroll
            for (int c = 0; c < 4; c++) acc[r][c] = 0.0f;
#pragma unroll 2
        for (int k4 = 0; k4 < 64; k4 += 4) {
            float4 xv[4];
#pragma unroll
            for (int r = 0; r < 4; r++)
                xv[r] = *(const float4*)&hs[(r0 + r) * 68 + k4];
            float4 w[4];
#pragma unroll
            for (int j = 0; j < 4; j++)
                w[j] = *(const float4*)&Wp1[(k4 + j) * 64 + c0];
#pragma unroll
            for (int r = 0; r < 4; r++) {
                const float xr[4] = {xv[r].x, xv[r].y, xv[r].z, xv[r].w};
#pragma unroll
                for (int j = 0; j < 4; j++) {
                    acc[r][0] = fmaf(xr[j], w[j].x, acc[r][0]);
                    acc[r][1] = fmaf(xr[j], w[j].y, acc[r][1]);
                    acc[r][2] = fmaf(xr[j], w[j].z, acc[r][2]);
                    acc[r][3] = fmaf(xr[j], w[j].w, acc[r][3]);
                }
            }
        }
        float4 b = *(const float4*)&bp1[c0];
#pragma unroll
        for (int r = 0; r < 4; r++) {
            float4 o = {fmaxf(acc[r][0] + b.x, 0.0f), fmaxf(acc[r][1] + b.y, 0.0f),
                        fmaxf(acc[r][2] + b.z, 0.0f), fmaxf(acc[r][3] + b.w, 0.0f)};
            *(float4*)&as_[(r0 + r) * 68 + c0] = o;
        }
    }
    __syncthreads();

    // GEMM B: z = a @ Wp2 + bp2
    {
        float acc[4][4];
#pragma unroll
        for (int r = 0; r < 4; r++)
#pragma unroll
            for (int c = 0; c < 4; c++) acc[r][c] = 0.0f;
#pragma unroll 2
        for (int k4 = 0; k4 < 64; k4 += 4) {
            float4 xv[4];
#pragma unroll
            for (int r = 0; r < 4; r++)
                xv[r] = *(const float4*)&as_[(r0 + r) * 68 + k4];
            float4 w[4];
#pragma unroll
            for (int j = 0; j < 4; j++)
                w[j] = *(const float4*)&Wp2[(k4 + j) * 64 + c0];
#pragma unroll
            for (int r = 0; r < 4; r++) {
                const float xr[4] = {xv[r].x, xv[r].y, xv[r].z, xv[r].w};
#pragma unroll
                for (int j = 0; j < 4; j++) {
                    acc[r][0] = fmaf(xr[j], w[j].x, acc[r][0]);
                    acc[r][1] = fmaf(xr[j], w[j].y, acc[r][1]);
                    acc[r][2] = fmaf(xr[j], w[j].z, acc[r][2]);
                    acc[r][3] = fmaf(xr[j], w[j].w, acc[r][3]);
                }
            }
        }
        float4 b = *(const float4*)&bp2[c0];
        float* zout = out + (size_t)N_NODES * 64;
#pragma unroll
        for (int r = 0; r < 4; r++) {
            int row = row0 + r0 + r;
            if (row < N_NODES) {
                float4 o = {acc[r][0] + b.x, acc[r][1] + b.y,
                            acc[r][2] + b.z, acc[r][3] + b.w};
                *(float4*)&zout[(size_t)row * 64 + c0] = o;
            }
        }
    }
}

// ---------------------------------------------------------------------------
// launch
// ---------------------------------------------------------------------------
extern "C" void kernel_launch(void* const* d_in, const int* in_sizes, int n_in,
                              void* d_out, int out_size, void* d_ws, size_t ws_size,
                              hipStream_t stream) {
    const float* x   = (const float*)d_in[0];
    const int*   ei  = (const int*)d_in[1];
    const float* W1  = (const float*)d_in[2];
    // b1 (d_in[3]) skipped: column-constant shift cancelled by BN1
    const float* g1  = (const float*)d_in[4];
    const float* be1 = (const float*)d_in[5];
    const float* W2  = (const float*)d_in[6];
    // b2 (d_in[7]) skipped: cancelled by BN2
    const float* g2  = (const float*)d_in[8];
    const float* be2 = (const float*)d_in[9];
    const float* Wp1 = (const float*)d_in[10];
    const float* bp1 = (const float*)d_in[11];
    const float* Wp2 = (const float*)d_in[12];
    const float* bp2 = (const float*)d_in[13];

    const int* src = ei;            // edge_index[0]
    const int* dst = ei + N_EDGES;  // edge_index[1]

    float* ws = (float*)d_ws;
    float* A    = ws;                          // h1s (N*128) / h2s (N*64)
    float* B    = A + (size_t)N_NODES * 128;   // out1 (N*128) / out2 (N*64)
    float* dinv = B + (size_t)N_NODES * 128;   // N
    float* st   = dinv + N_NODES;              // 768 floats of stats
    float* sc1  = st + 256;  float* sh1  = st + 384;
    float* sc2  = st + 640;  float* sh2  = st + 704;
    int* cnt      = (int*)(st + 768);          // N
    int* row_ptr  = cnt + N_NODES;             // N+1
    int* cursor   = row_ptr + N_NODES + 1;     // N
    int* csr_src  = cursor + N_NODES;          // E
    int* partials = csr_src + N_EDGES;         // NB_SCAN
    unsigned short* wb = (unsigned short*)(partials + NB_SCAN);  // 128*192 bf16 tiled
    unsigned short* w2h = wb + (size_t)F_HID * KP;               // 128*64 bf16
    unsigned short* w2l = w2h + (size_t)F_HID * F_OUT;           // 128*64 bf16

    // BN partials + stage-1 outputs, 16B aligned
    size_t off = (size_t)((char*)(w2l + F_HID * F_OUT) - (char*)d_ws);
    off = (off + 15) & ~(size_t)15;
    float* ps1  = (float*)((char*)d_ws + off);   // NBLK*128
    float* ps1q = ps1 + (size_t)NBLK * 128;      // NBLK*128
    float* ps2  = ps1q + (size_t)NBLK * 128;     // NBLK*64
    float* ps2q = ps2 + (size_t)NBLK * 64;       // NBLK*64
    float* ss1  = ps2q + (size_t)NBLK * 64;      // RBLK*128
    float* ss1q = ss1 + (size_t)RBLK * 128;      // RBLK*128
    float* ss2  = ss1q + (size_t)RBLK * 128;     // RBLK*64
    float* ss2q = ss2 + (size_t)RBLK * 64;       // RBLK*64

    hipMemsetAsync(st, 0, (768 + N_NODES) * sizeof(float), stream);

    const int EB = (N_EDGES + 255) / 256;
    const int GB64 = (N_NODES + 63) / 64;

    // CSR build + dinv (+ weight tiling kernels, independent)
    k_count<<<EB, 256, 0, stream>>>(dst, cnt);
    k_cvt_w<<<(F_HID * KP + 255) / 256, 256, 0, stream>>>(W1, wb);
    k_cvt_w2<<<(F_HID * F_OUT + 255) / 256, 256, 0, stream>>>(W2, w2h, w2l);
    k_scanA<<<NB_SCAN, 256, 0, stream>>>(cnt, partials);
    k_scanB<<<1, 1024, 0, stream>>>(partials, row_ptr);
    k_scanC<<<NB_SCAN, 256, 0, stream>>>(cnt, partials, row_ptr, cursor, dinv);
    k_scatter<<<EB, 256, 0, stream>>>(src, dst, cursor, csr_src);

    // layer 1 (fused cvt+MFMA GEMM, x read direct, 1 rowgroup/wave)
    k_mfma1<<<GB64C, 256, 0, stream>>>(x, wb, dinv, A);
    k_aggr<128, 32, 8><<<NBLK, 256, 0, stream>>>(A, row_ptr, csr_src, dinv, B, ps1, ps1q);
    k_bn_red<128><<<RBLK, 1024, 0, stream>>>(ps1, ps1q, ss1, ss1q);
    k_bn_fin<128><<<1, 1024, 0, stream>>>(ss1, ss1q, g1, be1, sc1, sh1);

    // layer 2 (BN1+relu fused into split-bf16 MFMA GEMM2)
    k_mfma2<<<GB128C, 256, 0, stream>>>(B, sc1, sh1, w2h, w2l, dinv, A);
    k_aggr<64, 16, 16><<<NBLK, 256, 0, stream>>>(A, row_ptr, csr_src, dinv, B, ps2, ps2q);
    k_bn_red<64><<<RBLK, 1024, 0, stream>>>(ps2, ps2q, ss2, ss2q);
    k_bn_fin<64><<<1, 1024, 0, stream>>>(ss2, ss2q, g2, be2, sc2, sh2);

    // BN2-apply + MLP head, writes both outputs
    k_final<<<GB64, 256, 0, stream>>>(B, sc2, sh2, Wp1, bp1, Wp2, bp2, (float*)d_out);
}

// Round 14
// 500.068 us; speedup vs baseline: 1.3639x; 1.0242x over previous
//
#include <hip/hip_runtime.h>
#include <hip/hip_bf16.h>

#define N_NODES 203769
#define N_EDGES 234355
#define F_IN    165
#define F_HID   128
#define F_OUT   64
#define BN_EPS  1e-5f
#define NB_SCAN 796   // ceil(N_NODES/256)
#define KP      192   // K padded to 6*32 for mfma_16x16x32
#define NBLK    4096  // aggregation grid
#define RBLK    32    // stage-1 reduction blocks
#define GB64C   3184  // ceil(N_NODES/64): k_mfma1 grid (4 waves x 1 rowgroup)
#define GB128C  1593  // ceil(N_NODES/128): k_mfma2 grid

typedef short bf16x8 __attribute__((ext_vector_type(8)));
typedef unsigned short u16x8 __attribute__((ext_vector_type(8)));
typedef float f32x4 __attribute__((ext_vector_type(4)));
typedef float f32x4u __attribute__((ext_vector_type(4), aligned(4)));  // 4B-aligned vec load

__device__ __forceinline__ unsigned short f2bf(float f) {
    unsigned int u = __builtin_bit_cast(unsigned int, f);
    u += 0x7fffu + ((u >> 16) & 1u);   // RNE
    return (unsigned short)(u >> 16);
}
__device__ __forceinline__ float bf2f(unsigned short h) {
    unsigned int u = ((unsigned int)h) << 16;
    return __builtin_bit_cast(float, u);
}

// ---------------------------------------------------------------------------
// CSR build
// ---------------------------------------------------------------------------
__global__ void k_count(const int* __restrict__ dst, int* __restrict__ cnt) {
    int e = blockIdx.x * 256 + threadIdx.x;
    if (e < N_EDGES) atomicAdd(&cnt[dst[e]], 1);
}

__global__ __launch_bounds__(256) void k_scanA(const int* __restrict__ cnt,
                                               int* __restrict__ partials) {
    __shared__ int sm[256];
    int t = threadIdx.x;
    int i = blockIdx.x * 256 + t;
    int v = (i < N_NODES) ? cnt[i] : 0;
    sm[t] = v;
    __syncthreads();
    for (int off = 128; off > 0; off >>= 1) {
        if (t < off) sm[t] += sm[t + off];
        __syncthreads();
    }
    if (t == 0) partials[blockIdx.x] = sm[0];
}

__global__ __launch_bounds__(1024) void k_scanB(int* __restrict__ partials,
                                                int* __restrict__ row_ptr) {
    __shared__ int sm[1024];
    int t = threadIdx.x;
    int v = (t < NB_SCAN) ? partials[t] : 0;
    sm[t] = v;
    __syncthreads();
    for (int off = 1; off < 1024; off <<= 1) {
        int add = (t >= off) ? sm[t - off] : 0;
        __syncthreads();
        sm[t] += add;
        __syncthreads();
    }
    if (t < NB_SCAN) partials[t] = sm[t] - v;   // exclusive
    if (t == NB_SCAN - 1) row_ptr[N_NODES] = sm[t];  // = E
}

__global__ __launch_bounds__(256) void k_scanC(const int* __restrict__ cnt,
                                               const int* __restrict__ partials,
                                               int* __restrict__ row_ptr,
                                               int* __restrict__ cursor,
                                               float* __restrict__ dinv) {
    __shared__ int sm[256];
    int t = threadIdx.x;
    int i = blockIdx.x * 256 + t;
    int v = (i < N_NODES) ? cnt[i] : 0;
    sm[t] = v;
    __syncthreads();
    for (int off = 1; off < 256; off <<= 1) {
        int add = (t >= off) ? sm[t - off] : 0;
        __syncthreads();
        sm[t] += add;
        __syncthreads();
    }
    if (i < N_NODES) {
        int p = partials[blockIdx.x] + sm[t] - v;  // exclusive prefix
        row_ptr[i] = p;
        cursor[i] = p;
        dinv[i] = rsqrtf(1.0f + (float)v);  // +1 self loop
    }
}

__global__ void k_scatter(const int* __restrict__ src, const int* __restrict__ dst,
                          int* __restrict__ cursor, int* __restrict__ csr_src) {
    int e = blockIdx.x * 256 + threadIdx.x;
    if (e < N_EDGES) {
        int pos = atomicAdd(&cursor[dst[e]], 1);
        csr_src[pos] = src[e];
    }
}

// ---------------------------------------------------------------------------
// W1 -> bf16, MFMA-fragment-tiled.
// ---------------------------------------------------------------------------
__global__ void k_cvt_w(const float* __restrict__ W1, unsigned short* __restrict__ wb) {
    int i = blockIdx.x * 256 + threadIdx.x;
    if (i < F_HID * KP) {
        int n = i / KP, k = i - n * KP;
        float v = (k < F_IN) ? W1[k * F_HID + n] : 0.0f;
        int ng = n >> 4, l16 = n & 15, kb = k >> 5, quad = (k >> 3) & 3, j = k & 7;
        wb[((((size_t)ng * 6 + kb) * 4 + quad) * 16 + l16) * 8 + j] = f2bf(v);
    }
}

// ---------------------------------------------------------------------------
// W2 -> split bf16 (hi + lo), MFMA-fragment-tiled.
// ---------------------------------------------------------------------------
__global__ void k_cvt_w2(const float* __restrict__ W2,
                         unsigned short* __restrict__ w2h,
                         unsigned short* __restrict__ w2l) {
    int i = blockIdx.x * 256 + threadIdx.x;
    if (i < F_HID * F_OUT) {
        int k = i / F_OUT, n = i - k * F_OUT;
        float v = W2[i];
        unsigned short h = f2bf(v);
        float lo = v - bf2f(h);
        int ng = n >> 4, l16 = n & 15, kb = k >> 5, quad = (k >> 3) & 3, j = k & 7;
        size_t idx = ((((size_t)ng * 4 + kb) * 4 + quad) * 16 + l16) * 8 + j;
        w2h[idx] = h;
        w2l[idx] = f2bf(lo);
    }
}

// ---------------------------------------------------------------------------
// GEMM1 (R15): h1s[N,128] = (x @ W1) * dinv[row], NO LDS / NO BARRIERS,
// direct x, ALL 12 x-loads hoisted before compute.
// R13 post-mortem: occ 25->44% at dur unchanged (97us, 1.9TB/s) => not
// residency-bound; VGPR=44 meant compiler buffered only ~2 of 12 loads
// per wave (occ x ILP constant). Fix: explicit load-all-then-compute,
// __launch_bounds__(256,4) caps 128 VGPR (peak live ~122) -> 4 waves/SIMD
// AND 12 loads in flight each: ~192KB/CU outstanding vs ~30KB.
// ---------------------------------------------------------------------------
__global__ __launch_bounds__(256, 4) void k_mfma1(const float* __restrict__ x,
                                                  const unsigned short* __restrict__ wb,
                                                  const float* __restrict__ dinv,
                                                  float* __restrict__ h1s) {
    const int t = threadIdx.x;
    const int wv = t >> 6;
    const int lane = t & 63;
    const int l16 = lane & 15;
    const int quad = lane >> 4;
    const int rg = blockIdx.x * 4 + wv;       // this wave's 16-row group
    const int lq = quad * 16 + l16;
    const int row = rg * 16 + l16;            // thread's fixed source row

    // ---- issue ALL x loads up front (independent; 12 dwordx4 in flight) ----
    f32x4u v0[6], v1[6];
    if (row < N_NODES) {
        const float* rp = x + (size_t)row * F_IN;
#pragma unroll
        for (int kb = 0; kb < 5; kb++) {
            const int k0 = kb * 32 + quad * 8;
            v0[kb] = *(const f32x4u*)(rp + k0);
            v1[kb] = *(const f32x4u*)(rp + k0 + 4);
        }
        {   // kb=5 padded tail: guarded scalar
            const int k0 = 160 + quad * 8;
#pragma unroll
            for (int j = 0; j < 4; j++) {
                int k = k0 + j;
                v0[5][j] = (k < F_IN) ? rp[k] : 0.0f;
            }
#pragma unroll
            for (int j = 0; j < 4; j++) {
                int k = k0 + 4 + j;
                v1[5][j] = (k < F_IN) ? rp[k] : 0.0f;
            }
        }
    } else {
#pragma unroll
        for (int kb = 0; kb < 6; kb++) {
            v0[kb] = (f32x4u){0.f, 0.f, 0.f, 0.f};
            v1[kb] = (f32x4u){0.f, 0.f, 0.f, 0.f};
        }
    }

    f32x4 acc[8];
#pragma unroll
    for (int nt = 0; nt < 8; nt++)
        acc[nt] = (f32x4){0.0f, 0.0f, 0.0f, 0.0f};

#pragma unroll
    for (int kb = 0; kb < 6; kb++) {
        u16x8 u;
        u[0] = f2bf(v0[kb][0]); u[1] = f2bf(v0[kb][1]);
        u[2] = f2bf(v0[kb][2]); u[3] = f2bf(v0[kb][3]);
        u[4] = f2bf(v1[kb][0]); u[5] = f2bf(v1[kb][1]);
        u[6] = f2bf(v1[kb][2]); u[7] = f2bf(v1[kb][3]);
        bf16x8 a = __builtin_bit_cast(bf16x8, u);
        bf16x8 b[8];
#pragma unroll
        for (int nt = 0; nt < 8; nt++)
            b[nt] = *(const bf16x8*)&wb[(((size_t)nt * 6 + kb) * 64 + lq) * 8];
#pragma unroll
        for (int nt = 0; nt < 8; nt++)
            acc[nt] = __builtin_amdgcn_mfma_f32_16x16x32_bf16(a, b[nt], acc[nt], 0, 0, 0);
    }

    // epilogue: C/D col = lane&15, row = quad*4 + reg; scale by dinv[row]
#pragma unroll
    for (int rgi = 0; rgi < 4; rgi++) {
        int grow = rg * 16 + quad * 4 + rgi;
        if (grow < N_NODES) {
            float dv = dinv[grow];
            float* orow = h1s + (size_t)grow * F_HID + l16;
#pragma unroll
            for (int nt = 0; nt < 8; nt++)
                orow[nt * 16] = acc[nt][rgi] * dv;
        }
    }
}

// ---------------------------------------------------------------------------
// GEMM2: h2s[N,64] = (relu(bn1(out1)) @ W2) * dinv, split-bf16 MFMA.
// ---------------------------------------------------------------------------
__global__ __launch_bounds__(256) void k_mfma2(const float* __restrict__ out1,
                                               const float* __restrict__ sc1,
                                               const float* __restrict__ sh1,
                                               const unsigned short* __restrict__ w2h,
                                               const unsigned short* __restrict__ w2l,
                                               const float* __restrict__ dinv,
                                               float* __restrict__ h2s) {
    const int t = threadIdx.x;
    const int wv = t >> 6;
    const int lane = t & 63;
    const int l16 = lane & 15;
    const int quad = lane >> 4;
    const int rg0 = blockIdx.x * 8 + wv * 2;
    const int lq = quad * 16 + l16;

    f32x4 acc[2][4];
#pragma unroll
    for (int mt = 0; mt < 2; mt++)
#pragma unroll
        for (int nt = 0; nt < 4; nt++)
            acc[mt][nt] = (f32x4){0.0f, 0.0f, 0.0f, 0.0f};

#pragma unroll
    for (int kb = 0; kb < 4; kb++) {
        const int k0 = kb * 32 + quad * 8;
        float4 sA = *(const float4*)&sc1[k0];
        float4 sB = *(const float4*)&sc1[k0 + 4];
        float4 hA = *(const float4*)&sh1[k0];
        float4 hB = *(const float4*)&sh1[k0 + 4];
        float sv[8] = {sA.x, sA.y, sA.z, sA.w, sB.x, sB.y, sB.z, sB.w};
        float hv[8] = {hA.x, hA.y, hA.z, hA.w, hB.x, hB.y, hB.z, hB.w};

        bf16x8 bh[4], bl[4];
#pragma unroll
        for (int nt = 0; nt < 4; nt++) {
            size_t u = ((((size_t)nt * 4 + kb) * 64) + lq) * 8;
            bh[nt] = *(const bf16x8*)&w2h[u];
            bl[nt] = *(const bf16x8*)&w2l[u];
        }

        bf16x8 ah[2], al[2];
#pragma unroll
        for (int mt = 0; mt < 2; mt++) {
            int row = (rg0 + mt) * 16 + l16;
            float v[8];
            if (row < N_NODES) {
                const float* rp = out1 + (size_t)row * F_HID + k0;
                float4 v0 = *(const float4*)rp;
                float4 v1 = *(const float4*)(rp + 4);
                v[0] = v0.x; v[1] = v0.y; v[2] = v0.z; v[3] = v0.w;
                v[4] = v1.x; v[5] = v1.y; v[6] = v1.z; v[7] = v1.w;
            } else {
#pragma unroll
                for (int j = 0; j < 8; j++) v[j] = 0.0f;
            }
            u16x8 uh, ul;
#pragma unroll
            for (int j = 0; j < 8; j++) {
                float f = fmaxf(fmaf(v[j], sv[j], hv[j]), 0.0f);
                unsigned short hb = f2bf(f);
                uh[j] = hb;
                ul[j] = f2bf(f - bf2f(hb));
            }
            ah[mt] = __builtin_bit_cast(bf16x8, uh);
            al[mt] = __builtin_bit_cast(bf16x8, ul);
        }

#pragma unroll
        for (int mt = 0; mt < 2; mt++)
#pragma unroll
            for (int nt = 0; nt < 4; nt++) {
                acc[mt][nt] = __builtin_amdgcn_mfma_f32_16x16x32_bf16(
                    ah[mt], bh[nt], acc[mt][nt], 0, 0, 0);
                acc[mt][nt] = __builtin_amdgcn_mfma_f32_16x16x32_bf16(
                    al[mt], bh[nt], acc[mt][nt], 0, 0, 0);
                acc[mt][nt] = __builtin_amdgcn_mfma_f32_16x16x32_bf16(
                    ah[mt], bl[nt], acc[mt][nt], 0, 0, 0);
            }
    }

#pragma unroll
    for (int mt = 0; mt < 2; mt++) {
#pragma unroll
        for (int rgi = 0; rgi < 4; rgi++) {
            int grow = (rg0 + mt) * 16 + quad * 4 + rgi;
            if (grow < N_NODES) {
                float dv = dinv[grow];
                float* orow = h2s + (size_t)grow * F_OUT + l16;
#pragma unroll
                for (int nt = 0; nt < 4; nt++)
                    orow[nt * 16] = acc[mt][nt][rgi] * dv;
            }
        }
    }
}

// ---------------------------------------------------------------------------
// Aggregation: single-pass CSR chase, BN stats as per-block partials.
// ---------------------------------------------------------------------------
template <int C, int TPN, int NPB>
__global__ __launch_bounds__(256) void k_aggr(const float* __restrict__ hs,
                                              const int* __restrict__ row_ptr,
                                              const int* __restrict__ csr_src,
                                              const float* __restrict__ dinv,
                                              float* __restrict__ out,
                                              float* __restrict__ psum,
                                              float* __restrict__ psq) {
    const int t = threadIdx.x;
    const int q = t & (TPN - 1);
    const int slot = t / TPN;
    float s0 = 0, s1 = 0, s2 = 0, s3 = 0;
    float q0 = 0, q1 = 0, q2 = 0, q3 = 0;

    for (int node = blockIdx.x * NPB + slot; node < N_NODES;
         node += gridDim.x * NPB) {
        int beg = row_ptr[node];
        int end = row_ptr[node + 1];
        float4 acc = *(const float4*)&hs[(size_t)node * C + q * 4];
        for (int e = beg; e < end; e++) {
            int s = csr_src[e];
            float4 v = *(const float4*)&hs[(size_t)s * C + q * 4];
            acc.x += v.x; acc.y += v.y; acc.z += v.z; acc.w += v.w;
        }
        float dv = dinv[node];
        acc.x *= dv; acc.y *= dv; acc.z *= dv; acc.w *= dv;
        *(float4*)&out[(size_t)node * C + q * 4] = acc;
        s0 += acc.x; s1 += acc.y; s2 += acc.z; s3 += acc.w;
        q0 = fmaf(acc.x, acc.x, q0); q1 = fmaf(acc.y, acc.y, q1);
        q2 = fmaf(acc.z, acc.z, q2); q3 = fmaf(acc.w, acc.w, q3);
    }

    __shared__ float sm[256 * 4];
    __shared__ float sq[256 * 4];
    sm[t * 4 + 0] = s0; sm[t * 4 + 1] = s1; sm[t * 4 + 2] = s2; sm[t * 4 + 3] = s3;
    sq[t * 4 + 0] = q0; sq[t * 4 + 1] = q1; sq[t * 4 + 2] = q2; sq[t * 4 + 3] = q3;
    __syncthreads();
    if (t < TPN) {
#pragma unroll
        for (int sl = 1; sl < NPB; sl++) {
            int u = (sl * TPN + t) * 4;
            s0 += sm[u + 0]; s1 += sm[u + 1]; s2 += sm[u + 2]; s3 += sm[u + 3];
            q0 += sq[u + 0]; q1 += sq[u + 1]; q2 += sq[u + 2]; q3 += sq[u + 3];
        }
        float4 o1 = {s0, s1, s2, s3};
        float4 o2 = {q0, q1, q2, q3};
        *(float4*)&psum[(size_t)blockIdx.x * C + t * 4] = o1;
        *(float4*)&psq [(size_t)blockIdx.x * C + t * 4] = o2;
    }
}

// ---------------------------------------------------------------------------
// BN partial reduction, stage 1: RBLK blocks x 1024 thr.
// ---------------------------------------------------------------------------
template <int C>
__global__ __launch_bounds__(1024) void k_bn_red(const float* __restrict__ psum,
                                                 const float* __restrict__ psq,
                                                 float* __restrict__ ss,
                                                 float* __restrict__ ssq) {
    const int t = threadIdx.x;
    const int c = t & (C - 1);
    const int gg = t / C;              // 0..G-1
    const int G = 1024 / C;
    const int ROWS = NBLK / RBLK;      // rows per block
    const int BPG = ROWS / G;          // rows per group
    const int r0 = blockIdx.x * ROWS + gg * BPG;
    float s = 0.0f, sq_ = 0.0f;
    for (int i = 0; i < BPG; i++) {
        int b = r0 + i;
        s   += psum[(size_t)b * C + c];
        sq_ += psq [(size_t)b * C + c];
    }
    __shared__ float sm[1024];
    __shared__ float s2[1024];
    sm[t] = s;
    s2[t] = sq_;
    __syncthreads();
    for (int off = G / 2; off > 0; off >>= 1) {
        if (gg < off) {
            sm[t] += sm[t + off * C];
            s2[t] += s2[t + off * C];
        }
        __syncthreads();
    }
    if (gg == 0) {
        ss [(size_t)blockIdx.x * C + c] = sm[c];
        ssq[(size_t)blockIdx.x * C + c] = s2[c];
    }
}

// ---------------------------------------------------------------------------
// BN partial reduction, stage 2: 1 block reduces RBLK rows -> scale/shift.
// ---------------------------------------------------------------------------
template <int C>
__global__ __launch_bounds__(1024) void k_bn_fin(const float* __restrict__ ss,
                                                 const float* __restrict__ ssq,
                                                 const float* __restrict__ g,
                                                 const float* __restrict__ be,
                                                 float* __restrict__ sc,
                                                 float* __restrict__ sh) {
    const int t = threadIdx.x;
    const int c = t & (C - 1);
    const int gg = t / C;          // 0..G-1
    const int G = 1024 / C;
    const int BPG = RBLK / G;      // 4 (C=128) or 2 (C=64)
    float s = 0.0f, sq_ = 0.0f;
    for (int i = 0; i < BPG; i++) {
        int b = gg * BPG + i;
        s   += ss [(size_t)b * C + c];
        sq_ += ssq[(size_t)b * C + c];
    }
    __shared__ float sm[1024];
    __shared__ float s2[1024];
    sm[t] = s;
    s2[t] = sq_;
    __syncthreads();
    for (int off = G / 2; off > 0; off >>= 1) {
        if (gg < off) {
            sm[t] += sm[t + off * C];
            s2[t] += s2[t + off * C];
        }
        __syncthreads();
    }
    if (gg == 0) {
        const float invn = 1.0f / (float)N_NODES;
        float mean = sm[c] * invn;
        float var = s2[c] * invn - mean * mean;
        float rstd = rsqrtf(var + BN_EPS);
        float scale = g[c] * rstd;
        sc[c] = scale;
        sh[c] = fmaf(-mean, scale, be[c]);
    }
}

// ---------------------------------------------------------------------------
// Final: hf = bn2(out2) -> d_out; z = relu(hf@Wp1+bp1)@Wp2+bp2
// ---------------------------------------------------------------------------
__global__ __launch_bounds__(256) void k_final(const float* __restrict__ out2,
                                               const float* __restrict__ sc2,
                                               const float* __restrict__ sh2,
                                               const float* __restrict__ Wp1,
                                               const float* __restrict__ bp1,
                                               const float* __restrict__ Wp2,
                                               const float* __restrict__ bp2,
                                               float* __restrict__ out) {
    __shared__ float hs[64 * 68];   // 17.4 KB
    __shared__ float as_[64 * 68];  // 17.4 KB
    const int row0 = blockIdx.x * 64;
    const int t = threadIdx.x;

    {
        const float4* src = (const float4*)out2;
        float4* dsth = (float4*)out;
#pragma unroll
        for (int i = 0; i < 4; i++) {
            int f4 = t + i * 256;         // 0..1023
            int r = f4 >> 4;
            int c4 = f4 & 15;
            int grow = row0 + r;
            float4 v = {0, 0, 0, 0};
            if (grow < N_NODES) v = src[(size_t)grow * 16 + c4];
            int c = c4 * 4;
            v.x = fmaf(v.x, sc2[c + 0], sh2[c + 0]);
            v.y = fmaf(v.y, sc2[c + 1], sh2[c + 1]);
            v.z = fmaf(v.z, sc2[c + 2], sh2[c + 2]);
            v.w = fmaf(v.w, sc2[c + 3], sh2[c + 3]);
            if (grow < N_NODES) dsth[(size_t)grow * 16 + c4] = v;
            *(float4*)&hs[r * 68 + c] = v;
        }
    }
    __syncthreads();

    const int c0 = (t & 15) * 4;
    const int r0 = (t >> 4) * 4;

    // GEMM A: a = relu(hs @ Wp1 + bp1)
    {
        float acc[4][4];
#pragma unroll
        for (int r = 0; r < 4; r++)
#pragma unroll
            for (int c = 0; c < 4; c++) acc[r][c] = 0.0f;
#pragma unroll 2
        for (int k4 = 0; k4 < 64; k4 += 4) {
            float4 xv[4];
#pragma unroll
            for (int r = 0; r < 4; r++)
                xv[r] = *(const float4*)&hs[(r0 + r) * 68 + k4];
            float4 w[4];
#pragma unroll
            for (int j = 0; j < 4; j++)
                w[j] = *(const float4*)&Wp1[(k4 + j) * 64 + c0];
#pragma unroll
            for (int r = 0; r < 4; r++) {
                const float xr[4] = {xv[r].x, xv[r].y, xv[r].z, xv[r].w};
#pragma unroll
                for (int j = 0; j < 4; j++) {
                    acc[r][0] = fmaf(xr[j], w[j].x, acc[r][0]);
                    acc[r][1] = fmaf(xr[j], w[j].y, acc[r][1]);
                    acc[r][2] = fmaf(xr[j], w[j].z, acc[r][2]);
                    acc[r][3] = fmaf(xr[j], w[j].w, acc[r][3]);
                }
            }
        }
        float4 b = *(const float4*)&bp1[c0];
#pragma unroll
        for (int r = 0; r < 4; r++) {
            float4 o = {fmaxf(acc[r][0] + b.x, 0.0f), fmaxf(acc[r][1] + b.y, 0.0f),
                        fmaxf(acc[r][2] + b.z, 0.0f), fmaxf(acc[r][3] + b.w, 0.0f)};
            *(float4*)&as_[(r0 + r) * 68 + c0] = o;
        }
    }
    __syncthreads();

    // GEMM B: z = a @ Wp2 + bp2
    {
        float acc[4][4];
#pragma unroll
        for (int r = 0; r < 4; r++)
#pragma unroll
            for (int c = 0; c < 4; c++) acc[r][c] = 0.0f;
#pragma unroll 2
        for (int k4 = 0; k4 < 64; k4 += 4) {
            float4 xv[4];
#pragma unroll
            for (int r = 0; r < 4; r++)
                xv[r] = *(const float4*)&as_[(r0 + r) * 68 + k4];
            float4 w[4];
#pragma unroll
            for (int j = 0; j < 4; j++)
                w[j] = *(const float4*)&Wp2[(k4 + j) * 64 + c0];
#pragma unroll
            for (int r = 0; r < 4; r++) {
                const float xr[4] = {xv[r].x, xv[r].y, xv[r].z, xv[r].w};
#pragma unroll
                for (int j = 0; j < 4; j++) {
                    acc[r][0] = fmaf(xr[j], w[j].x, acc[r][0]);
                    acc[r][1] = fmaf(xr[j], w[j].y, acc[r][1]);
                    acc[r][2] = fmaf(xr[j], w[j].z, acc[r][2]);
                    acc[r][3] = fmaf(xr[j], w[j].w, acc[r][3]);
                }
            }
        }
        float4 b = *(const float4*)&bp2[c0];
        float* zout = out + (size_t)N_NODES * 64;
#pragma unroll
        for (int r = 0; r < 4; r++) {
            int row = row0 + r0 + r;
            if (row < N_NODES) {
                float4 o = {acc[r][0] + b.x, acc[r][1] + b.y,
                            acc[r][2] + b.z, acc[r][3] + b.w};
                *(float4*)&zout[(size_t)row * 64 + c0] = o;
            }
        }
    }
}

// ---------------------------------------------------------------------------
// launch
// ---------------------------------------------------------------------------
extern "C" void kernel_launch(void* const* d_in, const int* in_sizes, int n_in,
                              void* d_out, int out_size, void* d_ws, size_t ws_size,
                              hipStream_t stream) {
    const float* x   = (const float*)d_in[0];
    const int*   ei  = (const int*)d_in[1];
    const float* W1  = (const float*)d_in[2];
    // b1 (d_in[3]) skipped: column-constant shift cancelled by BN1
    const float* g1  = (const float*)d_in[4];
    const float* be1 = (const float*)d_in[5];
    const float* W2  = (const float*)d_in[6];
    // b2 (d_in[7]) skipped: cancelled by BN2
    const float* g2  = (const float*)d_in[8];
    const float* be2 = (const float*)d_in[9];
    const float* Wp1 = (const float*)d_in[10];
    const float* bp1 = (const float*)d_in[11];
    const float* Wp2 = (const float*)d_in[12];
    const float* bp2 = (const float*)d_in[13];

    const int* src = ei;            // edge_index[0]
    const int* dst = ei + N_EDGES;  // edge_index[1]

    float* ws = (float*)d_ws;
    float* A    = ws;                          // h1s (N*128) / h2s (N*64)
    float* B    = A + (size_t)N_NODES * 128;   // out1 (N*128) / out2 (N*64)
    float* dinv = B + (size_t)N_NODES * 128;   // N
    float* st   = dinv + N_NODES;              // 768 floats of stats
    float* sc1  = st + 256;  float* sh1  = st + 384;
    float* sc2  = st + 640;  float* sh2  = st + 704;
    int* cnt      = (int*)(st + 768);          // N
    int* row_ptr  = cnt + N_NODES;             // N+1
    int* cursor   = row_ptr + N_NODES + 1;     // N
    int* csr_src  = cursor + N_NODES;          // E
    int* partials = csr_src + N_EDGES;         // NB_SCAN
    unsigned short* wb = (unsigned short*)(partials + NB_SCAN);  // 128*192 bf16 tiled
    unsigned short* w2h = wb + (size_t)F_HID * KP;               // 128*64 bf16
    unsigned short* w2l = w2h + (size_t)F_HID * F_OUT;           // 128*64 bf16

    // BN partials + stage-1 outputs, 16B aligned
    size_t off = (size_t)((char*)(w2l + F_HID * F_OUT) - (char*)d_ws);
    off = (off + 15) & ~(size_t)15;
    float* ps1  = (float*)((char*)d_ws + off);   // NBLK*128
    float* ps1q = ps1 + (size_t)NBLK * 128;      // NBLK*128
    float* ps2  = ps1q + (size_t)NBLK * 128;     // NBLK*64
    float* ps2q = ps2 + (size_t)NBLK * 64;       // NBLK*64
    float* ss1  = ps2q + (size_t)NBLK * 64;      // RBLK*128
    float* ss1q = ss1 + (size_t)RBLK * 128;      // RBLK*128
    float* ss2  = ss1q + (size_t)RBLK * 128;     // RBLK*64
    float* ss2q = ss2 + (size_t)RBLK * 64;       // RBLK*64

    hipMemsetAsync(st, 0, (768 + N_NODES) * sizeof(float), stream);

    const int EB = (N_EDGES + 255) / 256;
    const int GB64 = (N_NODES + 63) / 64;

    // CSR build + dinv (+ weight tiling kernels, independent)
    k_count<<<EB, 256, 0, stream>>>(dst, cnt);
    k_cvt_w<<<(F_HID * KP + 255) / 256, 256, 0, stream>>>(W1, wb);
    k_cvt_w2<<<(F_HID * F_OUT + 255) / 256, 256, 0, stream>>>(W2, w2h, w2l);
    k_scanA<<<NB_SCAN, 256, 0, stream>>>(cnt, partials);
    k_scanB<<<1, 1024, 0, stream>>>(partials, row_ptr);
    k_scanC<<<NB_SCAN, 256, 0, stream>>>(cnt, partials, row_ptr, cursor, dinv);
    k_scatter<<<EB, 256, 0, stream>>>(src, dst, cursor, csr_src);

    // layer 1 (fused cvt+MFMA GEMM, x read direct, loads hoisted)
    k_mfma1<<<GB64C, 256, 0, stream>>>(x, wb, dinv, A);
    k_aggr<128, 32, 8><<<NBLK, 256, 0, stream>>>(A, row_ptr, csr_src, dinv, B, ps1, ps1q);
    k_bn_red<128><<<RBLK, 1024, 0, stream>>>(ps1, ps1q, ss1, ss1q);
    k_bn_fin<128><<<1, 1024, 0, stream>>>(ss1, ss1q, g1, be1, sc1, sh1);

    // layer 2 (BN1+relu fused into split-bf16 MFMA GEMM2)
    k_mfma2<<<GB128C, 256, 0, stream>>>(B, sc1, sh1, w2h, w2l, dinv, A);
    k_aggr<64, 16, 16><<<NBLK, 256, 0, stream>>>(A, row_ptr, csr_src, dinv, B, ps2, ps2q);
    k_bn_red<64><<<RBLK, 1024, 0, stream>>>(ps2, ps2q, ss2, ss2q);
    k_bn_fin<64><<<1, 1024, 0, stream>>>(ss2, ss2q, g2, be2, sc2, sh2);

    // BN2-apply + MLP head, writes both outputs
    k_final<<<GB64, 256, 0, stream>>>(B, sc2, sh2, Wp1, bp1, Wp2, bp2, (float*)d_out);
}